// Round 2
// baseline (343.618 us; speedup 1.0000x reference)
//
#include <hip/hip_runtime.h>
#include <hip/hip_bf16.h>
#include <hip/hip_cooperative_groups.h>

namespace cg = cooperative_groups;

#define B_ 32
#define N_ 512
#define D_ 512
#define E_ 8
#define P_ 96
#define KC 25
#define H_ 4
#define DK 128
#define HE 32
#define BN 16384

typedef short short8 __attribute__((ext_vector_type(8)));
typedef float f32x4 __attribute__((ext_vector_type(4)));

// ws offsets (floats). cnt zeroed + s2 computed race-free inside k_head.
#define OCNT  4096      /* 256 ints (8 counters strided by 32) */
#define OS2   4352      /* 768 */
#define OM    5120      /* 16384 */
#define OC    21504     /* 32 */
#define OA    21536     /* 524288: raw logits half-0 */
#define OATT  676896    /* 131072 */
#define OTOK  807968    /* 131072 ints */
#define OWEFF 939040    /* 786432 bf16 = 393216 float slots */
#define OZC   1332256   /* 24576 */
#define OUP   1356832   /* 4194304: u partials */
#define OA1   5551136   /* 524288: raw logits half-1 */

__device__ __forceinline__ float b2f(short s) {
  unsigned u = ((unsigned)(unsigned short)s) << 16;
  return __builtin_bit_cast(float, u);
}
__device__ __forceinline__ unsigned short f2b(float f) {
  return __builtin_bit_cast(unsigned short, __float2bfloat16(f));
}

// k_head: 3 independent weight-preprocessing jobs in ONE dispatch.
__global__ __launch_bounds__(256) void k_head(const float* __restrict__ router,
        const float* __restrict__ Wq, const float* __restrict__ bq,
        const float* __restrict__ Wk, const float* __restrict__ bk,
        const float* __restrict__ Wp, const float* __restrict__ Wc,
        float* __restrict__ M, float* __restrict__ c,
        int* __restrict__ cnt, float* __restrict__ s2,
        __hip_bfloat16* __restrict__ weff) {
  __shared__ float sm[5824];
  int bid = blockIdx.x;
  int tid = threadIdx.x;
  if (bid < 64) {
    float* rs = sm;
    float* ps = sm + 512;
    float* qs = sm + 768;
    int he = bid >> 1, ch = bid & 1;
    int h = he >> 3, e = he & 7;
    for (int i = tid; i < 512; i += 256) rs[i] = router[e * D_ + i];
    __syncthreads();
    {
      int j = tid & 127, dh = tid >> 7;
      const float* wq = Wq + h * 128 + j;
      float acc = 0.f;
      for (int d = dh * 256; d < dh * 256 + 256; d += 4) {
        acc = fmaf(rs[d], wq[d * D_], acc);
        acc = fmaf(rs[d + 1], wq[(d + 1) * D_], acc);
        acc = fmaf(rs[d + 2], wq[(d + 2) * D_], acc);
        acc = fmaf(rs[d + 3], wq[(d + 3) * D_], acc);
      }
      ps[dh * 128 + j] = acc;
    }
    __syncthreads();
    if (tid < 128) qs[tid] = ps[tid] + ps[128 + tid] + bq[h * 128 + tid];
    __syncthreads();
    {
      int d0 = ch * 256 + tid;
      const float* wrow = Wk + d0 * D_ + h * 128;
      float acc = 0.f;
      for (int jj = 0; jj < 128; jj += 4) {
        float4 wv = *(const float4*)(wrow + jj);
        acc = fmaf(wv.x, qs[jj], acc);
        acc = fmaf(wv.y, qs[jj + 1], acc);
        acc = fmaf(wv.z, qs[jj + 2], acc);
        acc = fmaf(wv.w, qs[jj + 3], acc);
      }
      M[he * D_ + d0] = acc;
    }
    if (ch == 0 && tid < 64) {
      float s = qs[tid] * bk[h * 128 + tid] + qs[tid + 64] * bk[h * 128 + tid + 64];
#pragma unroll
      for (int off = 32; off; off >>= 1) s += __shfl_xor(s, off);
      if (tid == 0) c[he] = s;
    }
  } else if (bid < 192) {
    float* T = sm;
    float* wcs = sm + 5760;
    int eb = bid - 64;
    int e = eb >> 4, mc = eb & 15;
    int lo = mc * 32 - 12;
    for (int idx = tid; idx < 56 * 24; idx += 256) {
      int lp = idx / 24, p4 = (idx - lp * 24) * 4;
      int l = lo + lp;
      float4 v = {0.f, 0.f, 0.f, 0.f};
      if (l >= 0 && l < D_) v = *(const float4*)(Wp + (e * D_ + l) * P_ + p4);
      T[p4 * 60 + lp] = v.x; T[(p4 + 1) * 60 + lp] = v.y;
      T[(p4 + 2) * 60 + lp] = v.z; T[(p4 + 3) * 60 + lp] = v.w;
    }
    if (tid < 50) wcs[tid] = Wc[e * 2 * KC + tid];
    __syncthreads();
    int m = tid & 31, pg = tid >> 5;
#pragma unroll
    for (int j = 0; j < 2; ++j)
      for (int k2 = 0; k2 < 12; ++k2) {
        int p = pg * 12 + k2;
        float acc = 0.f;
#pragma unroll
        for (int k = 0; k < KC; ++k)
          acc = fmaf(wcs[j * 25 + k], T[p * 60 + m - k + 24], acc);
        weff[(((e * 2 + j) * P_ + p) << 9) + mc * 32 + m] = __float2bfloat16(acc);
      }
  } else {
    int e = bid - 192;
    if (bid == 192) cnt[tid] = 0;
    if (tid < 192) {
      int p = tid % 96, lg = tid / 96;
      float s = 0.f;
      const float* wp = Wp + e * D_ * P_ + p;
      for (int l = lg * 256; l < lg * 256 + 256; ++l) s += wp[l * P_];
      sm[lg * 96 + p] = s;
    }
    __syncthreads();
    if (tid < 96) s2[e * 96 + tid] = sm[tid] + sm[96 + tid];
  }
}

// logits: register-tiled LDS GEMM. Block = (b, 64-token tile, K-half).
__global__ __launch_bounds__(128) void k_logits(const float* __restrict__ x,
        const float* __restrict__ M, float* __restrict__ A0,
        float* __restrict__ A1) {
  __shared__ float xs[64 * 132];
  __shared__ float Ms[32 * 132];
  int dh = blockIdx.x & 1;
  int nt8 = (blockIdx.x >> 1) & 7;
  int b = blockIdx.x >> 4;
  int tid = threadIdx.x;
  const float* xb = x + (b * N_ + nt8 * 64) * D_ + dh * 256;
  const float* Mb = M + dh * 256;
  float acc[4][4] = {{0.f}};
  for (int kc = 0; kc < 2; ++kc) {
    for (int idx = tid; idx < 2048; idx += 128) {
      int r = idx >> 5, c4 = (idx & 31) * 4;
      *(float4*)(xs + r * 132 + c4) = *(const float4*)(xb + r * D_ + kc * 128 + c4);
    }
    for (int idx = tid; idx < 1024; idx += 128) {
      int r = idx >> 5, c4 = (idx & 31) * 4;
      *(float4*)(Ms + r * 132 + c4) = *(const float4*)(Mb + r * D_ + kc * 128 + c4);
    }
    __syncthreads();
    int nt = tid & 15, ht = tid >> 4;
#pragma unroll 4
    for (int d4 = 0; d4 < 128; d4 += 4) {
      float4 xv[4], mv[4];
#pragma unroll
      for (int i = 0; i < 4; ++i)
        xv[i] = *(const float4*)(xs + (nt + 16 * i) * 132 + d4);
#pragma unroll
      for (int j = 0; j < 4; ++j)
        mv[j] = *(const float4*)(Ms + (ht + 8 * j) * 132 + d4);
#pragma unroll
      for (int i = 0; i < 4; ++i)
#pragma unroll
        for (int j = 0; j < 4; ++j) {
          float s = acc[i][j];
          s = fmaf(xv[i].x, mv[j].x, s);
          s = fmaf(xv[i].y, mv[j].y, s);
          s = fmaf(xv[i].z, mv[j].z, s);
          s = fmaf(xv[i].w, mv[j].w, s);
          acc[i][j] = s;
        }
    }
    __syncthreads();
  }
  int nt = tid & 15, ht = tid >> 4;
  float* Ad = dh ? A1 : A0;
#pragma unroll
  for (int j = 0; j < 4; ++j) {
    int he = ht + 8 * j;
#pragma unroll
    for (int i = 0; i < 4; ++i)
      Ad[(b * HE + he) * N_ + nt8 * 64 + nt + 16 * i] = acc[i][j];
  }
}

// Cooperative mega-kernel: u3 -> vo -> route -> final with grid-wide syncs.
// 256 blocks x 512 threads, 1 block/CU guaranteed resident.
__global__ __launch_bounds__(512, 2) void k_mega(
        const float* __restrict__ x, const float* __restrict__ A0,
        const float* __restrict__ A1, const float* __restrict__ c,
        float* __restrict__ up,
        const float* __restrict__ Wv, const float* __restrict__ bv,
        const float* __restrict__ Wo, const float* __restrict__ bo,
        float* __restrict__ att,
        const __hip_bfloat16* __restrict__ weff, const float* __restrict__ s2,
        const float* __restrict__ bc, const float* __restrict__ bp,
        int* __restrict__ cnt, int* __restrict__ tok, float* __restrict__ zc,
        float* __restrict__ out) {
  __shared__ __align__(16) char smem[35200];
  cg::grid_group grid = cg::this_grid();
  int tid = threadIdx.x;

  // ---------------- Phase U: softmax + u-partials (old k_u3) ----------------
  {
    float* As = (float*)smem;            // 64*33 floats
    float* mS = (float*)(smem + 8448);   // 32
    float* sS = (float*)(smem + 8576);   // 32
    int nq = blockIdx.x & 7, b = blockIdx.x >> 3;
    const float scale = 0.08838834764831845f;
    {
      int wv = tid >> 6, lane = tid & 63;
      int he = wv * 4 + (lane >> 4);
      int l16 = lane & 15;
      const float* r0 = A0 + (b * HE + he) * N_;
      const float* r1 = A1 + (b * HE + he) * N_;
      float cc = c[he];
      float v[32];
      float m = -1e30f;
#pragma unroll
      for (int k = 0; k < 32; ++k) {
        int n = l16 + k * 16;
        float vv = scale * (r0[n] + r1[n] + cc);
        v[k] = vv;
        m = fmaxf(m, vv);
      }
      m = fmaxf(m, __shfl_xor(m, 1)); m = fmaxf(m, __shfl_xor(m, 2));
      m = fmaxf(m, __shfl_xor(m, 4)); m = fmaxf(m, __shfl_xor(m, 8));
      float s = 0.f;
#pragma unroll
      for (int k = 0; k < 32; ++k) s += expf(v[k] - m);
      s += __shfl_xor(s, 1); s += __shfl_xor(s, 2);
      s += __shfl_xor(s, 4); s += __shfl_xor(s, 8);
      if (l16 == 0) { mS[he] = m; sS[he] = 1.0f / s; }
    }
    __syncthreads();
    for (int idx = tid; idx < 64 * 32; idx += 512) {
      int n = idx & 63, he = idx >> 6;
      int gn = nq * 64 + n;
      float vv = scale * (A0[(b * HE + he) * N_ + gn] + A1[(b * HE + he) * N_ + gn]
                          + c[he]);
      As[n * 33 + he] = expf(vv - mS[he]) * sS[he];
    }
    __syncthreads();
    int dq = tid & 127, hg = tid >> 7;
    const float* xb = x + (b * N_ + nq * 64) * D_ + dq * 4;
    float acc[8][4];
#pragma unroll
    for (int j = 0; j < 8; ++j)
#pragma unroll
      for (int k = 0; k < 4; ++k) acc[j][k] = 0.f;
    for (int n = 0; n < 64; ++n) {
      float4 xv = *(const float4*)(xb + n * D_);
      const float* ar = As + n * 33 + hg * 8;
#pragma unroll
      for (int j = 0; j < 8; ++j) {
        float a = ar[j];
        acc[j][0] = fmaf(a, xv.x, acc[j][0]);
        acc[j][1] = fmaf(a, xv.y, acc[j][1]);
        acc[j][2] = fmaf(a, xv.z, acc[j][2]);
        acc[j][3] = fmaf(a, xv.w, acc[j][3]);
      }
    }
    float* o = up + (((b * 8 + nq) * HE) + hg * 8) * D_ + dq * 4;
#pragma unroll
    for (int j = 0; j < 8; ++j) {
      float4 v; v.x = acc[j][0]; v.y = acc[j][1]; v.z = acc[j][2]; v.w = acc[j][3];
      *(float4*)(o + j * D_) = v;
    }
  }
  grid.sync();

  // ---------------- Phase V: fused V+O projection (old k_vo3) ----------------
  {
    float* us   = (float*)smem;            // 4*512
    float* part = (float*)(smem + 8192);   // 4*512
    float* ap_s = (float*)(smem + 16384);  // 512
    int b = blockIdx.x >> 3, e = blockIdx.x & 7;
    for (int idx = tid; idx < 4 * 128; idx += 512) {
      int h = idx >> 7, d4 = (idx & 127) * 4;
      const float* base = up + ((b * 8) * HE + h * 8 + e) * D_ + d4;
      float4 s = {0.f, 0.f, 0.f, 0.f};
#pragma unroll
      for (int nq = 0; nq < 8; ++nq) {
        float4 v = *(const float4*)(base + nq * HE * D_);
        s.x += v.x; s.y += v.y; s.z += v.z; s.w += v.w;
      }
      *(float4*)(us + h * 512 + d4) = s;
    }
    __syncthreads();
    {
      int cch = tid >> 7, j = tid & 127;
      int i0 = j * 4;
      int h = j >> 5;
      const float* ur = us + h * 512;
      const float* wv = Wv + i0;
      float4 acc = {0.f, 0.f, 0.f, 0.f};
      int d0 = cch * 128;
#pragma unroll 4
      for (int d = d0; d < d0 + 128; ++d) {
        float4 wq = *(const float4*)(wv + d * D_);
        float a = ur[d];
        acc.x = fmaf(a, wq.x, acc.x);
        acc.y = fmaf(a, wq.y, acc.y);
        acc.z = fmaf(a, wq.z, acc.z);
        acc.w = fmaf(a, wq.w, acc.w);
      }
      *(float4*)(part + cch * 512 + i0) = acc;
    }
    __syncthreads();
    ap_s[tid] = part[tid] + part[512 + tid] + part[1024 + tid] + part[1536 + tid]
                + bv[tid];
    __syncthreads();
    {
      int cch = tid >> 7, j = tid & 127;
      int o0 = j * 4;
      const float* wo = Wo + o0;
      float4 acc = {0.f, 0.f, 0.f, 0.f};
      int i0 = cch * 128;
#pragma unroll 4
      for (int i = i0; i < i0 + 128; ++i) {
        float4 wq = *(const float4*)(wo + i * D_);
        float a = ap_s[i];
        acc.x = fmaf(a, wq.x, acc.x);
        acc.y = fmaf(a, wq.y, acc.y);
        acc.z = fmaf(a, wq.z, acc.z);
        acc.w = fmaf(a, wq.w, acc.w);
      }
      *(float4*)(part + cch * 512 + o0) = acc;
    }
    __syncthreads();
    att[(b * E_ + e) * D_ + tid] = part[tid] + part[512 + tid] + part[1024 + tid]
                                   + part[1536 + tid] + bo[tid];
  }
  grid.sync();

  // ---------------- Phase R: routing + fused zc (64-token tiles) -------------
  {
    float* att_s = (float*)smem;             // 8*512
    float* rn    = (float*)(smem + 16384);   // 8
    float* red   = (float*)(smem + 16416);   // 8*520
    int*   blist = (int*)(smem + 33056);     // 8*64
    int*   bcnt  = (int*)(smem + 35104);     // 8
    int b = blockIdx.x >> 3, tile = blockIdx.x & 7;
    for (int idx = tid; idx < 1024; idx += 512)
      *(float4*)(att_s + idx * 4) = *(const float4*)(att + b * E_ * D_ + idx * 4);
    if (tid < 8) bcnt[tid] = 0;
    __syncthreads();
    if (tid < 256) {
      int e = tid >> 5, l = tid & 31;
      float s = 0.f;
      for (int d0 = l; d0 < D_; d0 += 32) {
        float v = att_s[e * D_ + d0];
        s = fmaf(v, v, s);
      }
#pragma unroll
      for (int off = 16; off; off >>= 1) s += __shfl_xor(s, off);
      if (l == 0) rn[e] = 1.0f / sqrtf(s);
    }
    __syncthreads();
    int w = tid >> 6, lane = tid & 63;
    int e2 = lane & 7, ch = lane >> 3;
    float* rw = red + w * 520;
    for (int i = 0; i < 8; ++i) {
      int t = b * N_ + tile * 64 + w * 8 + i;
      const float* xp = x + t * D_ + lane * 8;
      float4 xa = *(const float4*)xp;
      float4 xb4 = *(const float4*)(xp + 4);
      float p[8];
#pragma unroll
      for (int e = 0; e < 8; ++e) {
        const float* apt = att_s + e * D_ + lane * 8;
        float4 a0 = *(const float4*)apt;
        float4 a1 = *(const float4*)(apt + 4);
        float s = a0.x * xa.x;
        s = fmaf(a0.y, xa.y, s); s = fmaf(a0.z, xa.z, s); s = fmaf(a0.w, xa.w, s);
        s = fmaf(a1.x, xb4.x, s); s = fmaf(a1.y, xb4.y, s);
        s = fmaf(a1.z, xb4.z, s); s = fmaf(a1.w, xb4.w, s);
        p[e] = s;
      }
#pragma unroll
      for (int e = 0; e < 8; ++e) rw[e * 65 + lane] = p[e];
      float s = 0.f;
#pragma unroll
      for (int k = 0; k < 8; ++k) s += rw[e2 * 65 + ch * 8 + k];
      s += __shfl_xor(s, 8); s += __shfl_xor(s, 16); s += __shfl_xor(s, 32);
      float sc = s * rn[e2];
      int be = e2;
#pragma unroll
      for (int off = 1; off < 8; off <<= 1) {
        float o = __shfl_xor(sc, off);
        int oe = __shfl_xor(be, off);
        if (o > sc || (o == sc && oe < be)) { sc = o; be = oe; }
      }
      if (lane == 0) {
        int slot = atomicAdd(&bcnt[be], 1);
        blist[be * 64 + slot] = t;
      }
    }
    __syncthreads();
    if (tid < 256) {
      int e = tid >> 5, r = tid & 31;
      int ce = bcnt[e];
      int gs = 0;
      if (r == 0 && ce > 0) gs = atomicAdd(&cnt[e * 32], ce);
      gs = __shfl(gs, (tid & 63) & 32);
      for (int k2 = r; k2 < ce; k2 += 32) tok[e * BN + gs + k2] = blist[e * 64 + k2];
    }
    int grp = tid >> 4, l16 = tid & 15;
    int ez = tile;
    const float* arow = att_s + ez * D_;
    for (int r = 0; r < 3; ++r) {
      int p = r * 32 + grp;
      const short* wrow = (const short*)weff + (((ez * 2 + 1) * P_ + p) << 9);
      float acc = 0.f;
#pragma unroll
      for (int seg = 0; seg < 4; ++seg) {
        int d = seg * 128 + l16 * 8;
        short8 w8 = *(const short8*)(wrow + d);
        const float* a8 = arow + d;
        acc = fmaf(a8[0], b2f(w8[0]), acc); acc = fmaf(a8[1], b2f(w8[1]), acc);
        acc = fmaf(a8[2], b2f(w8[2]), acc); acc = fmaf(a8[3], b2f(w8[3]), acc);
        acc = fmaf(a8[4], b2f(w8[4]), acc); acc = fmaf(a8[5], b2f(w8[5]), acc);
        acc = fmaf(a8[6], b2f(w8[6]), acc); acc = fmaf(a8[7], b2f(w8[7]), acc);
      }
      acc += __shfl_xor(acc, 1); acc += __shfl_xor(acc, 2);
      acc += __shfl_xor(acc, 4); acc += __shfl_xor(acc, 8);
      if (l16 == 0)
        zc[(b * E_ + ez) * P_ + p] = acc + bc[ez] * s2[ez * 96 + p] + bp[ez * 96 + p];
    }
  }
  grid.sync();

  // ---------------- Phase F: grouped final GEMM (grid-strided) ---------------
  {
    unsigned short* xsb = (unsigned short*)smem;   // 32*520
    int* toks = (int*)(smem + 33280);              // 32
    int cl_e[E_], bs[E_ + 1];
    bs[0] = 0;
#pragma unroll
    for (int e = 0; e < E_; ++e) {
      cl_e[e] = cnt[e * 32];
      bs[e + 1] = bs[e] + ((cl_e[e] + 31) >> 5);
    }
    int nb = bs[E_];
    for (int g = blockIdx.x; g < nb; g += 256) {
      int e = 0;
#pragma unroll
      for (int k = 1; k < E_; ++k) if (g >= bs[k]) e = k;
      int base = (g - bs[e]) * 32;
      int cnt_e = cl_e[e];
      int cl = cnt_e - base; if (cl > 32) cl = 32;
      if (tid < 32) toks[tid] = (tid < cl) ? tok[e * BN + base + tid] : tok[e * BN + base];
      __syncthreads();
      for (int idx = tid; idx < 32 * 128; idx += 512) {
        int r = idx >> 7, c4 = (idx & 127) * 4;
        float4 v = *(const float4*)(x + toks[r] * D_ + c4);
        ushort4 u4;
        u4.x = f2b(v.x); u4.y = f2b(v.y); u4.z = f2b(v.z); u4.w = f2b(v.w);
        *(ushort4*)(xsb + r * 520 + c4) = u4;
      }
      __syncthreads();
      int wave = tid >> 6, lane = tid & 63;
      if (wave < 4) {
        int mw = wave & 1, nw = wave >> 1;
        int m16 = lane & 15, quad = lane >> 4;
        const short* w0 = (const short*)(weff + (e * 2 + 0) * P_ * D_);
        f32x4 acc[3];
#pragma unroll
        for (int nt = 0; nt < 3; ++nt) acc[nt] = (f32x4){0.f, 0.f, 0.f, 0.f};
        const short* arow = (const short*)xsb + (mw * 16 + m16) * 520 + quad * 8;
        const short* brow = w0 + (nw * 48 + m16) * D_ + quad * 8;
        for (int kt = 0; kt < 16; ++kt) {
          int koff = kt * 32;
          short8 a = *(const short8*)(arow + koff);
#pragma unroll
          for (int nt = 0; nt < 3; ++nt) {
            short8 bf = *(const short8*)(brow + nt * 16 * D_ + koff);
            acc[nt] = __builtin_amdgcn_mfma_f32_16x16x32_bf16(a, bf, acc[nt], 0, 0, 0);
          }
        }
#pragma unroll
        for (int nt = 0; nt < 3; ++nt)
#pragma unroll
          for (int rr = 0; rr < 4; ++rr) {
            int row = mw * 16 + quad * 4 + rr;
            if (row < cl) {
              int tg = toks[row];
              int bb = tg >> 9;
              int p = nw * 48 + nt * 16 + m16;
              out[tg * P_ + p] = acc[nt][rr] + zc[(bb * E_ + e) * P_ + p];
            }
          }
      }
      __syncthreads();
    }
  }
}

extern "C" void kernel_launch(void* const* d_in, const int* in_sizes, int n_in,
                              void* d_out, int out_size, void* d_ws, size_t ws_size,
                              hipStream_t stream) {
  const float* x      = (const float*)d_in[0];
  const float* router = (const float*)d_in[1];
  const float* Wq     = (const float*)d_in[2];
  const float* bq     = (const float*)d_in[3];
  const float* Wk     = (const float*)d_in[4];
  const float* bk     = (const float*)d_in[5];
  const float* Wv     = (const float*)d_in[6];
  const float* bv     = (const float*)d_in[7];
  const float* Wo     = (const float*)d_in[8];
  const float* bo     = (const float*)d_in[9];
  const float* Wc     = (const float*)d_in[10];
  const float* bc     = (const float*)d_in[11];
  const float* Wp     = (const float*)d_in[12];
  const float* bp     = (const float*)d_in[13];
  float* out = (float*)d_out;
  float* w = (float*)d_ws;

  int*   cnt  = (int*)(w + OCNT);
  float* s2   = w + OS2;
  float* M    = w + OM;
  float* c    = w + OC;
  float* A0   = w + OA;
  float* A1   = w + OA1;
  float* att  = w + OATT;
  int*   tok  = (int*)(w + OTOK);
  __hip_bfloat16* weff = (__hip_bfloat16*)(w + OWEFF);
  float* zc   = w + OZC;
  float* up   = w + OUP;

  k_head<<<200, 256, 0, stream>>>(router, Wq, bq, Wk, bk, Wp, Wc, M, c, cnt, s2, weff);
  k_logits<<<512, 128, 0, stream>>>(x, M, A0, A1);

  {
    const float* xa = x;
    const float* A0a = A0; const float* A1a = A1; const float* ca = c;
    float* upa = up;
    const float* Wva = Wv; const float* bva = bv;
    const float* Woa = Wo; const float* boa = bo;
    float* atta = att;
    const __hip_bfloat16* weffa = weff; const float* s2a = s2;
    const float* bca = bc; const float* bpa = bp;
    int* cnta = cnt; int* toka = tok; float* zca = zc;
    float* outa = out;
    void* args[] = {&xa, &A0a, &A1a, &ca, &upa, &Wva, &bva, &Woa, &boa, &atta,
                    &weffa, &s2a, &bca, &bpa, &cnta, &toka, &zca, &outa};
    hipLaunchCooperativeKernel(reinterpret_cast<void*>(k_mega), dim3(256),
                               dim3(512), args, 0, stream);
  }
}

// Round 3
// 228.578 us; speedup vs baseline: 1.5033x; 1.5033x over previous
//
#include <hip/hip_runtime.h>
#include <hip/hip_bf16.h>

#define B_ 32
#define N_ 512
#define D_ 512
#define E_ 8
#define P_ 96
#define KC 25
#define H_ 4
#define DK 128
#define HE 32
#define BN 16384

typedef short short8 __attribute__((ext_vector_type(8)));
typedef float f32x4 __attribute__((ext_vector_type(4)));

// ws offsets (floats). cnt zeroed + s2 computed race-free inside k_head.
#define OCNT  4096      /* 256 ints (8 counters strided by 32) */
#define OS2   4352      /* 768 */
#define OM    5120      /* 16384 */
#define OC    21504     /* 32 */
#define OA    21536     /* 524288: raw logits half-0 */
#define OATT  676896    /* 131072 */
#define OTOK  807968    /* 131072 ints */
#define OWEFF 939040    /* 786432 bf16 = 393216 float slots */
#define OZC   1332256   /* 24576 */
#define OA1   5551136   /* 524288: raw logits half-1 */
#define OUP16 16777216  /* 8388608 floats: u partials, 16 nq-tiles */

__device__ __forceinline__ float b2f(short s) {
  unsigned u = ((unsigned)(unsigned short)s) << 16;
  return __builtin_bit_cast(float, u);
}
__device__ __forceinline__ unsigned short f2b(float f) {
  return __builtin_bit_cast(unsigned short, __float2bfloat16(f));
}

// k_head: 3 independent weight-preprocessing jobs in ONE dispatch.
__global__ __launch_bounds__(256) void k_head(const float* __restrict__ router,
        const float* __restrict__ Wq, const float* __restrict__ bq,
        const float* __restrict__ Wk, const float* __restrict__ bk,
        const float* __restrict__ Wp, const float* __restrict__ Wc,
        float* __restrict__ M, float* __restrict__ c,
        int* __restrict__ cnt, float* __restrict__ s2,
        __hip_bfloat16* __restrict__ weff) {
  __shared__ float sm[5824];
  int bid = blockIdx.x;
  int tid = threadIdx.x;
  if (bid < 64) {
    float* rs = sm;
    float* ps = sm + 512;
    float* qs = sm + 768;
    int he = bid >> 1, ch = bid & 1;
    int h = he >> 3, e = he & 7;
    for (int i = tid; i < 512; i += 256) rs[i] = router[e * D_ + i];
    __syncthreads();
    {
      int j = tid & 127, dh = tid >> 7;
      const float* wq = Wq + h * 128 + j;
      float acc = 0.f;
      for (int d = dh * 256; d < dh * 256 + 256; d += 4) {
        acc = fmaf(rs[d], wq[d * D_], acc);
        acc = fmaf(rs[d + 1], wq[(d + 1) * D_], acc);
        acc = fmaf(rs[d + 2], wq[(d + 2) * D_], acc);
        acc = fmaf(rs[d + 3], wq[(d + 3) * D_], acc);
      }
      ps[dh * 128 + j] = acc;
    }
    __syncthreads();
    if (tid < 128) qs[tid] = ps[tid] + ps[128 + tid] + bq[h * 128 + tid];
    __syncthreads();
    {
      int d0 = ch * 256 + tid;
      const float* wrow = Wk + d0 * D_ + h * 128;
      float acc = 0.f;
      for (int jj = 0; jj < 128; jj += 4) {
        float4 wv = *(const float4*)(wrow + jj);
        acc = fmaf(wv.x, qs[jj], acc);
        acc = fmaf(wv.y, qs[jj + 1], acc);
        acc = fmaf(wv.z, qs[jj + 2], acc);
        acc = fmaf(wv.w, qs[jj + 3], acc);
      }
      M[he * D_ + d0] = acc;
    }
    if (ch == 0 && tid < 64) {
      float s = qs[tid] * bk[h * 128 + tid] + qs[tid + 64] * bk[h * 128 + tid + 64];
#pragma unroll
      for (int off = 32; off; off >>= 1) s += __shfl_xor(s, off);
      if (tid == 0) c[he] = s;
    }
  } else if (bid < 192) {
    float* T = sm;
    float* wcs = sm + 5760;
    int eb = bid - 64;
    int e = eb >> 4, mc = eb & 15;
    int lo = mc * 32 - 12;
    for (int idx = tid; idx < 56 * 24; idx += 256) {
      int lp = idx / 24, p4 = (idx - lp * 24) * 4;
      int l = lo + lp;
      float4 v = {0.f, 0.f, 0.f, 0.f};
      if (l >= 0 && l < D_) v = *(const float4*)(Wp + (e * D_ + l) * P_ + p4);
      T[p4 * 60 + lp] = v.x; T[(p4 + 1) * 60 + lp] = v.y;
      T[(p4 + 2) * 60 + lp] = v.z; T[(p4 + 3) * 60 + lp] = v.w;
    }
    if (tid < 50) wcs[tid] = Wc[e * 2 * KC + tid];
    __syncthreads();
    int m = tid & 31, pg = tid >> 5;
#pragma unroll
    for (int j = 0; j < 2; ++j)
      for (int k2 = 0; k2 < 12; ++k2) {
        int p = pg * 12 + k2;
        float acc = 0.f;
#pragma unroll
        for (int k = 0; k < KC; ++k)
          acc = fmaf(wcs[j * 25 + k], T[p * 60 + m - k + 24], acc);
        weff[(((e * 2 + j) * P_ + p) << 9) + mc * 32 + m] = __float2bfloat16(acc);
      }
  } else {
    int e = bid - 192;
    if (bid == 192) cnt[tid] = 0;
    if (tid < 192) {
      int p = tid % 96, lg = tid / 96;
      float s = 0.f;
      const float* wp = Wp + e * D_ * P_ + p;
      for (int l = lg * 256; l < lg * 256 + 256; ++l) s += wp[l * P_];
      sm[lg * 96 + p] = s;
    }
    __syncthreads();
    if (tid < 96) s2[e * 96 + tid] = sm[tid] + sm[96 + tid];
  }
}

// logits: register-tiled LDS GEMM. Block = (b, 64-token tile, K-half).
__global__ __launch_bounds__(128) void k_logits(const float* __restrict__ x,
        const float* __restrict__ M, float* __restrict__ A0,
        float* __restrict__ A1) {
  __shared__ float xs[64 * 132];
  __shared__ float Ms[32 * 132];
  int dh = blockIdx.x & 1;
  int nt8 = (blockIdx.x >> 1) & 7;
  int b = blockIdx.x >> 4;
  int tid = threadIdx.x;
  const float* xb = x + (b * N_ + nt8 * 64) * D_ + dh * 256;
  const float* Mb = M + dh * 256;
  float acc[4][4] = {{0.f}};
  for (int kc = 0; kc < 2; ++kc) {
    for (int idx = tid; idx < 2048; idx += 128) {
      int r = idx >> 5, c4 = (idx & 31) * 4;
      *(float4*)(xs + r * 132 + c4) = *(const float4*)(xb + r * D_ + kc * 128 + c4);
    }
    for (int idx = tid; idx < 1024; idx += 128) {
      int r = idx >> 5, c4 = (idx & 31) * 4;
      *(float4*)(Ms + r * 132 + c4) = *(const float4*)(Mb + r * D_ + kc * 128 + c4);
    }
    __syncthreads();
    int nt = tid & 15, ht = tid >> 4;
#pragma unroll 4
    for (int d4 = 0; d4 < 128; d4 += 4) {
      float4 xv[4], mv[4];
#pragma unroll
      for (int i = 0; i < 4; ++i)
        xv[i] = *(const float4*)(xs + (nt + 16 * i) * 132 + d4);
#pragma unroll
      for (int j = 0; j < 4; ++j)
        mv[j] = *(const float4*)(Ms + (ht + 8 * j) * 132 + d4);
#pragma unroll
      for (int i = 0; i < 4; ++i)
#pragma unroll
        for (int j = 0; j < 4; ++j) {
          float s = acc[i][j];
          s = fmaf(xv[i].x, mv[j].x, s);
          s = fmaf(xv[i].y, mv[j].y, s);
          s = fmaf(xv[i].z, mv[j].z, s);
          s = fmaf(xv[i].w, mv[j].w, s);
          acc[i][j] = s;
        }
    }
    __syncthreads();
  }
  int nt = tid & 15, ht = tid >> 4;
  float* Ad = dh ? A1 : A0;
#pragma unroll
  for (int j = 0; j < 4; ++j) {
    int he = ht + 8 * j;
#pragma unroll
    for (int i = 0; i < 4; ++i)
      Ad[(b * HE + he) * N_ + nt8 * 64 + nt + 16 * i] = acc[i][j];
  }
}

// fused softmax + u-partials: block (nq, b) with 32-token tiles, 512 threads.
// 512 blocks -> 2 blocks/CU, 16 waves/CU (was 1 block/CU, 8 waves) for
// latency hiding in the u-GEMM.
__global__ __launch_bounds__(512) void k_u3(const float* __restrict__ x,
        const float* __restrict__ A0, const float* __restrict__ A1,
        const float* __restrict__ c, float* __restrict__ up) {
  __shared__ float As[32 * 33];
  __shared__ float mS[32], sS[32];
  int nq = blockIdx.x, b = blockIdx.y;
  int tid = threadIdx.x;
  const float scale = 0.08838834764831845f;
  {
    int wv = tid >> 6, lane = tid & 63;
    int he = wv * 4 + (lane >> 4);
    int l16 = lane & 15;
    const float* r0 = A0 + (b * HE + he) * N_;
    const float* r1 = A1 + (b * HE + he) * N_;
    float cc = c[he];
    float v[32];
    float m = -1e30f;
#pragma unroll
    for (int k = 0; k < 32; ++k) {
      int n = l16 + k * 16;
      float vv = scale * (r0[n] + r1[n] + cc);
      v[k] = vv;
      m = fmaxf(m, vv);
    }
    m = fmaxf(m, __shfl_xor(m, 1)); m = fmaxf(m, __shfl_xor(m, 2));
    m = fmaxf(m, __shfl_xor(m, 4)); m = fmaxf(m, __shfl_xor(m, 8));
    float s = 0.f;
#pragma unroll
    for (int k = 0; k < 32; ++k) s += expf(v[k] - m);
    s += __shfl_xor(s, 1); s += __shfl_xor(s, 2);
    s += __shfl_xor(s, 4); s += __shfl_xor(s, 8);
    if (l16 == 0) { mS[he] = m; sS[he] = 1.0f / s; }
  }
  __syncthreads();
  for (int idx = tid; idx < 32 * 32; idx += 512) {
    int n = idx & 31, he = idx >> 5;
    int gn = nq * 32 + n;
    float vv = scale * (A0[(b * HE + he) * N_ + gn] + A1[(b * HE + he) * N_ + gn]
                        + c[he]);
    As[n * 33 + he] = expf(vv - mS[he]) * sS[he];
  }
  __syncthreads();
  int dq = tid & 127, hg = tid >> 7;
  const float* xb = x + (b * N_ + nq * 32) * D_ + dq * 4;
  float acc[8][4];
#pragma unroll
  for (int j = 0; j < 8; ++j)
#pragma unroll
    for (int k = 0; k < 4; ++k) acc[j][k] = 0.f;
#pragma unroll 2
  for (int n = 0; n < 32; ++n) {
    float4 xv = *(const float4*)(xb + n * D_);
    const float* ar = As + n * 33 + hg * 8;
#pragma unroll
    for (int j = 0; j < 8; ++j) {
      float a = ar[j];
      acc[j][0] = fmaf(a, xv.x, acc[j][0]);
      acc[j][1] = fmaf(a, xv.y, acc[j][1]);
      acc[j][2] = fmaf(a, xv.z, acc[j][2]);
      acc[j][3] = fmaf(a, xv.w, acc[j][3]);
    }
  }
  float* o = up + (((b * 16 + nq) * HE) + hg * 8) * D_ + dq * 4;
#pragma unroll
  for (int j = 0; j < 8; ++j) {
    float4 v; v.x = acc[j][0]; v.y = acc[j][1]; v.z = acc[j][2]; v.w = acc[j][3];
    *(float4*)(o + j * D_) = v;
  }
}

// fused V+O projection v3, job = (b,e). 256 blocks x 512 thr. 16 nq-partials.
__global__ __launch_bounds__(512) void k_vo3(const float* __restrict__ up,
        const float* __restrict__ Wv, const float* __restrict__ bv,
        const float* __restrict__ Wo, const float* __restrict__ bo,
        float* __restrict__ att) {
  __shared__ float us[4 * 512];
  __shared__ float part[4 * 512];
  __shared__ float ap_s[512];
  int b = blockIdx.x >> 3, e = blockIdx.x & 7;
  int tid = threadIdx.x;
  for (int idx = tid; idx < 4 * 128; idx += 512) {
    int h = idx >> 7, d4 = (idx & 127) * 4;
    const float* base = up + ((b * 16) * HE + h * 8 + e) * D_ + d4;
    float4 s = {0.f, 0.f, 0.f, 0.f};
#pragma unroll
    for (int nq = 0; nq < 16; ++nq) {
      float4 v = *(const float4*)(base + nq * HE * D_);
      s.x += v.x; s.y += v.y; s.z += v.z; s.w += v.w;
    }
    *(float4*)(us + h * 512 + d4) = s;
  }
  __syncthreads();
  {
    int cch = tid >> 7, j = tid & 127;
    int i0 = j * 4;
    int h = j >> 5;
    const float* ur = us + h * 512;
    const float* wv = Wv + i0;
    float4 acc = {0.f, 0.f, 0.f, 0.f};
    int d0 = cch * 128;
#pragma unroll 4
    for (int d = d0; d < d0 + 128; ++d) {
      float4 wq = *(const float4*)(wv + d * D_);
      float a = ur[d];
      acc.x = fmaf(a, wq.x, acc.x);
      acc.y = fmaf(a, wq.y, acc.y);
      acc.z = fmaf(a, wq.z, acc.z);
      acc.w = fmaf(a, wq.w, acc.w);
    }
    *(float4*)(part + cch * 512 + i0) = acc;
  }
  __syncthreads();
  ap_s[tid] = part[tid] + part[512 + tid] + part[1024 + tid] + part[1536 + tid]
              + bv[tid];
  __syncthreads();
  {
    int cch = tid >> 7, j = tid & 127;
    int o0 = j * 4;
    const float* wo = Wo + o0;
    float4 acc = {0.f, 0.f, 0.f, 0.f};
    int i0 = cch * 128;
#pragma unroll 4
    for (int i = i0; i < i0 + 128; ++i) {
      float4 wq = *(const float4*)(wo + i * D_);
      float a = ap_s[i];
      acc.x = fmaf(a, wq.x, acc.x);
      acc.y = fmaf(a, wq.y, acc.y);
      acc.z = fmaf(a, wq.z, acc.z);
      acc.w = fmaf(a, wq.w, acc.w);
    }
    *(float4*)(part + cch * 512 + o0) = acc;
  }
  __syncthreads();
  att[(b * E_ + e) * D_ + tid] = part[tid] + part[512 + tid] + part[1024 + tid]
                                 + part[1536 + tid] + bo[tid];
}

// routing (one wave per token) + fused zc
__global__ __launch_bounds__(256) void k_route2(const float* __restrict__ x,
        const float* __restrict__ att, const __hip_bfloat16* __restrict__ weff,
        const float* __restrict__ s2, const float* __restrict__ bc,
        const float* __restrict__ bp, int* __restrict__ cnt,
        int* __restrict__ tok, float* __restrict__ zc) {
  __shared__ float att_s[8 * D_];
  __shared__ float rn[8];
  __shared__ float red[4][520];
  __shared__ int blist[8][32];
  __shared__ int bcnt[8];
  int b = blockIdx.x >> 4, tile = blockIdx.x & 15;
  for (int idx = threadIdx.x; idx < 1024; idx += 256)
    *(float4*)(att_s + idx * 4) = *(const float4*)(att + b * E_ * D_ + idx * 4);
  if (threadIdx.x < 8) bcnt[threadIdx.x] = 0;
  __syncthreads();
  {
    int e = threadIdx.x >> 5, l = threadIdx.x & 31;
    float s = 0.f;
    for (int d0 = l; d0 < D_; d0 += 32) {
      float v = att_s[e * D_ + d0];
      s = fmaf(v, v, s);
    }
#pragma unroll
    for (int off = 16; off; off >>= 1) s += __shfl_xor(s, off);
    if (l == 0) rn[e] = 1.0f / sqrtf(s);
  }
  __syncthreads();
  int w = threadIdx.x >> 6, lane = threadIdx.x & 63;
  int e2 = lane & 7, ch = lane >> 3;
  float* rw = red[w];
  for (int i = 0; i < 8; ++i) {
    int t = b * N_ + tile * 32 + w * 8 + i;
    const float* xp = x + t * D_ + lane * 8;
    float4 xa = *(const float4*)xp;
    float4 xb4 = *(const float4*)(xp + 4);
    float p[8];
#pragma unroll
    for (int e = 0; e < 8; ++e) {
      const float* apt = att_s + e * D_ + lane * 8;
      float4 a0 = *(const float4*)apt;
      float4 a1 = *(const float4*)(apt + 4);
      float s = a0.x * xa.x;
      s = fmaf(a0.y, xa.y, s); s = fmaf(a0.z, xa.z, s); s = fmaf(a0.w, xa.w, s);
      s = fmaf(a1.x, xb4.x, s); s = fmaf(a1.y, xb4.y, s);
      s = fmaf(a1.z, xb4.z, s); s = fmaf(a1.w, xb4.w, s);
      p[e] = s;
    }
#pragma unroll
    for (int e = 0; e < 8; ++e) rw[e * 65 + lane] = p[e];
    float s = 0.f;
#pragma unroll
    for (int k = 0; k < 8; ++k) s += rw[e2 * 65 + ch * 8 + k];
    s += __shfl_xor(s, 8); s += __shfl_xor(s, 16); s += __shfl_xor(s, 32);
    float sc = s * rn[e2];
    int be = e2;
#pragma unroll
    for (int off = 1; off < 8; off <<= 1) {
      float o = __shfl_xor(sc, off);
      int oe = __shfl_xor(be, off);
      if (o > sc || (o == sc && oe < be)) { sc = o; be = oe; }
    }
    if (lane == 0) {
      int slot = atomicAdd(&bcnt[be], 1);
      blist[be][slot] = t;
    }
  }
  __syncthreads();
  {
    int e = threadIdx.x >> 5, r = threadIdx.x & 31;
    int ce = bcnt[e];
    int gs = 0;
    if (r == 0 && ce > 0) gs = atomicAdd(&cnt[e * 32], ce);
    gs = __shfl(gs, (threadIdx.x & 63) & 32);
    for (int k2 = r; k2 < ce; k2 += 32) tok[e * BN + gs + k2] = blist[e][k2];
  }
  int grp = threadIdx.x >> 4, l16 = threadIdx.x & 15;
  for (int r = 0; r < 3; ++r) {
    int P = tile * 48 + r * 16 + grp;
    int ez = P / 96, p = P - ez * 96;
    const short* wrow = (const short*)weff + (((ez * 2 + 1) * P_ + p) << 9);
    const float* arow = att_s + ez * D_;
    float acc = 0.f;
#pragma unroll
    for (int seg = 0; seg < 4; ++seg) {
      int d = seg * 128 + l16 * 8;
      short8 w8 = *(const short8*)(wrow + d);
      const float* a8 = arow + d;
      acc = fmaf(a8[0], b2f(w8[0]), acc); acc = fmaf(a8[1], b2f(w8[1]), acc);
      acc = fmaf(a8[2], b2f(w8[2]), acc); acc = fmaf(a8[3], b2f(w8[3]), acc);
      acc = fmaf(a8[4], b2f(w8[4]), acc); acc = fmaf(a8[5], b2f(w8[5]), acc);
      acc = fmaf(a8[6], b2f(w8[6]), acc); acc = fmaf(a8[7], b2f(w8[7]), acc);
    }
    acc += __shfl_xor(acc, 1); acc += __shfl_xor(acc, 2);
    acc += __shfl_xor(acc, 4); acc += __shfl_xor(acc, 8);
    if (l16 == 0)
      zc[(b * E_ + ez) * P_ + p] = acc + bc[ez] * s2[ez * 96 + p] + bp[ez * 96 + p];
  }
}

// grouped final GEMM: exactly-sized segmented grid, 256 threads (4 waves),
// 32 tokens x 96 cols per block.
__global__ __launch_bounds__(256) void k_final(const float* __restrict__ x,
        const __hip_bfloat16* __restrict__ weff, const float* __restrict__ zc,
        const int* __restrict__ cnt, const int* __restrict__ tok,
        float* __restrict__ out) {
  __shared__ __align__(16) unsigned short xsb[32 * 520];
  __shared__ int toks[32];
  int g = blockIdx.x;
  int cl_e[E_], bs[E_ + 1];
  bs[0] = 0;
#pragma unroll
  for (int e = 0; e < E_; ++e) {
    cl_e[e] = cnt[e * 32];
    bs[e + 1] = bs[e] + ((cl_e[e] + 31) >> 5);
  }
  if (g >= bs[E_]) return;
  int e = 0;
#pragma unroll
  for (int k = 1; k < E_; ++k) if (g >= bs[k]) e = k;
  int base = (g - bs[e]) * 32;
  int cnt_e = cl_e[e];
  int cl = cnt_e - base; if (cl > 32) cl = 32;
  int tid = threadIdx.x;
  if (tid < 32) toks[tid] = (tid < cl) ? tok[e * BN + base + tid] : tok[e * BN + base];
  __syncthreads();
  for (int idx = tid; idx < 32 * 128; idx += 256) {
    int r = idx >> 7, c4 = (idx & 127) * 4;
    float4 v = *(const float4*)(x + toks[r] * D_ + c4);
    ushort4 u4;
    u4.x = f2b(v.x); u4.y = f2b(v.y); u4.z = f2b(v.z); u4.w = f2b(v.w);
    *(ushort4*)(xsb + r * 520 + c4) = u4;
  }
  __syncthreads();
  int wave = tid >> 6, lane = tid & 63;
  int mw = wave & 1, nw = wave >> 1;
  int m16 = lane & 15, quad = lane >> 4;
  const short* w0 = (const short*)(weff + (e * 2 + 0) * P_ * D_);
  f32x4 acc[3];
#pragma unroll
  for (int nt = 0; nt < 3; ++nt) acc[nt] = (f32x4){0.f, 0.f, 0.f, 0.f};
  const short* arow = (const short*)xsb + (mw * 16 + m16) * 520 + quad * 8;
  const short* brow = w0 + (nw * 48 + m16) * D_ + quad * 8;
  for (int kt = 0; kt < 16; ++kt) {
    int koff = kt * 32;
    short8 a = *(const short8*)(arow + koff);
#pragma unroll
    for (int nt = 0; nt < 3; ++nt) {
      short8 bf = *(const short8*)(brow + nt * 16 * D_ + koff);
      acc[nt] = __builtin_amdgcn_mfma_f32_16x16x32_bf16(a, bf, acc[nt], 0, 0, 0);
    }
  }
#pragma unroll
  for (int nt = 0; nt < 3; ++nt)
#pragma unroll
    for (int rr = 0; rr < 4; ++rr) {
      int row = mw * 16 + quad * 4 + rr;
      if (row < cl) {
        int tg = toks[row];
        int bb = tg >> 9;
        int p = nw * 48 + nt * 16 + m16;
        out[tg * P_ + p] = acc[nt][rr] + zc[(bb * E_ + e) * P_ + p];
      }
    }
}

extern "C" void kernel_launch(void* const* d_in, const int* in_sizes, int n_in,
                              void* d_out, int out_size, void* d_ws, size_t ws_size,
                              hipStream_t stream) {
  const float* x      = (const float*)d_in[0];
  const float* router = (const float*)d_in[1];
  const float* Wq     = (const float*)d_in[2];
  const float* bq     = (const float*)d_in[3];
  const float* Wk     = (const float*)d_in[4];
  const float* bk     = (const float*)d_in[5];
  const float* Wv     = (const float*)d_in[6];
  const float* bv     = (const float*)d_in[7];
  const float* Wo     = (const float*)d_in[8];
  const float* bo     = (const float*)d_in[9];
  const float* Wc     = (const float*)d_in[10];
  const float* bc     = (const float*)d_in[11];
  const float* Wp     = (const float*)d_in[12];
  const float* bp     = (const float*)d_in[13];
  float* out = (float*)d_out;
  float* w = (float*)d_ws;

  int*   cnt  = (int*)(w + OCNT);
  float* s2   = w + OS2;
  float* M    = w + OM;
  float* c    = w + OC;
  float* A0   = w + OA;
  float* A1   = w + OA1;
  float* att  = w + OATT;
  int*   tok  = (int*)(w + OTOK);
  __hip_bfloat16* weff = (__hip_bfloat16*)(w + OWEFF);
  float* zc   = w + OZC;
  float* up   = w + OUP16;

  k_head<<<200, 256, 0, stream>>>(router, Wq, bq, Wk, bk, Wp, Wc, M, c, cnt, s2, weff);
  k_logits<<<512, 128, 0, stream>>>(x, M, A0, A1);
  k_u3<<<dim3(16, 32), 512, 0, stream>>>(x, A0, A1, c, up);
  k_vo3<<<256, 512, 0, stream>>>(up, Wv, bv, Wo, bo, att);
  k_route2<<<512, 256, 0, stream>>>(x, att, weff, s2, bc, bp, cnt, tok, zc);
  k_final<<<520, 256, 0, stream>>>(x, weff, zc, cnt, tok, out);
}

// Round 4
// 208.699 us; speedup vs baseline: 1.6465x; 1.0953x over previous
//
#include <hip/hip_runtime.h>
#include <hip/hip_bf16.h>

#define B_ 32
#define N_ 512
#define D_ 512
#define E_ 8
#define P_ 96
#define KC 25
#define H_ 4
#define DK 128
#define HE 32
#define BN 16384

typedef short short8 __attribute__((ext_vector_type(8)));
typedef float f32x4 __attribute__((ext_vector_type(4)));

// ws offsets (floats). cnt zeroed + s2 computed race-free inside k_head.
#define OCNT  4096      /* 256 ints (8 counters strided by 32) */
#define OS2   4352      /* 768 */
#define OM    5120      /* 16384 */
#define OC    21504     /* 32 */
#define OA    21536     /* 524288: raw logits half-0 */
#define OATT  676896    /* 131072 */
#define OTOK  807968    /* 131072 ints */
#define OWEFF 939040    /* 786432 bf16 = 393216 float slots */
#define OZC   1332256   /* 24576 */
#define OA1   5551136   /* 524288: raw logits half-1 */
#define OAP   16777216  /* 131072: ap[b,e,512] V-projection output */

__device__ __forceinline__ float b2f(short s) {
  unsigned u = ((unsigned)(unsigned short)s) << 16;
  return __builtin_bit_cast(float, u);
}
__device__ __forceinline__ unsigned short f2b(float f) {
  return __builtin_bit_cast(unsigned short, __float2bfloat16(f));
}

// k_head: 3 independent weight-preprocessing jobs in ONE dispatch.
__global__ __launch_bounds__(256) void k_head(const float* __restrict__ router,
        const float* __restrict__ Wq, const float* __restrict__ bq,
        const float* __restrict__ Wk, const float* __restrict__ bk,
        const float* __restrict__ Wp, const float* __restrict__ Wc,
        float* __restrict__ M, float* __restrict__ c,
        int* __restrict__ cnt, float* __restrict__ s2,
        __hip_bfloat16* __restrict__ weff) {
  __shared__ float sm[5824];
  int bid = blockIdx.x;
  int tid = threadIdx.x;
  if (bid < 64) {
    float* rs = sm;
    float* ps = sm + 512;
    float* qs = sm + 768;
    int he = bid >> 1, ch = bid & 1;
    int h = he >> 3, e = he & 7;
    for (int i = tid; i < 512; i += 256) rs[i] = router[e * D_ + i];
    __syncthreads();
    {
      int j = tid & 127, dh = tid >> 7;
      const float* wq = Wq + h * 128 + j;
      float acc = 0.f;
      for (int d = dh * 256; d < dh * 256 + 256; d += 4) {
        acc = fmaf(rs[d], wq[d * D_], acc);
        acc = fmaf(rs[d + 1], wq[(d + 1) * D_], acc);
        acc = fmaf(rs[d + 2], wq[(d + 2) * D_], acc);
        acc = fmaf(rs[d + 3], wq[(d + 3) * D_], acc);
      }
      ps[dh * 128 + j] = acc;
    }
    __syncthreads();
    if (tid < 128) qs[tid] = ps[tid] + ps[128 + tid] + bq[h * 128 + tid];
    __syncthreads();
    {
      int d0 = ch * 256 + tid;
      const float* wrow = Wk + d0 * D_ + h * 128;
      float acc = 0.f;
      for (int jj = 0; jj < 128; jj += 4) {
        float4 wv = *(const float4*)(wrow + jj);
        acc = fmaf(wv.x, qs[jj], acc);
        acc = fmaf(wv.y, qs[jj + 1], acc);
        acc = fmaf(wv.z, qs[jj + 2], acc);
        acc = fmaf(wv.w, qs[jj + 3], acc);
      }
      M[he * D_ + d0] = acc;
    }
    if (ch == 0 && tid < 64) {
      float s = qs[tid] * bk[h * 128 + tid] + qs[tid + 64] * bk[h * 128 + tid + 64];
#pragma unroll
      for (int off = 32; off; off >>= 1) s += __shfl_xor(s, off);
      if (tid == 0) c[he] = s;
    }
  } else if (bid < 192) {
    float* T = sm;
    float* wcs = sm + 5760;
    int eb = bid - 64;
    int e = eb >> 4, mc = eb & 15;
    int lo = mc * 32 - 12;
    for (int idx = tid; idx < 56 * 24; idx += 256) {
      int lp = idx / 24, p4 = (idx - lp * 24) * 4;
      int l = lo + lp;
      float4 v = {0.f, 0.f, 0.f, 0.f};
      if (l >= 0 && l < D_) v = *(const float4*)(Wp + (e * D_ + l) * P_ + p4);
      T[p4 * 60 + lp] = v.x; T[(p4 + 1) * 60 + lp] = v.y;
      T[(p4 + 2) * 60 + lp] = v.z; T[(p4 + 3) * 60 + lp] = v.w;
    }
    if (tid < 50) wcs[tid] = Wc[e * 2 * KC + tid];
    __syncthreads();
    int m = tid & 31, pg = tid >> 5;
#pragma unroll
    for (int j = 0; j < 2; ++j)
      for (int k2 = 0; k2 < 12; ++k2) {
        int p = pg * 12 + k2;
        float acc = 0.f;
#pragma unroll
        for (int k = 0; k < KC; ++k)
          acc = fmaf(wcs[j * 25 + k], T[p * 60 + m - k + 24], acc);
        weff[(((e * 2 + j) * P_ + p) << 9) + mc * 32 + m] = __float2bfloat16(acc);
      }
  } else {
    int e = bid - 192;
    if (bid == 192) cnt[tid] = 0;
    if (tid < 192) {
      int p = tid % 96, lg = tid / 96;
      float s = 0.f;
      const float* wp = Wp + e * D_ * P_ + p;
      for (int l = lg * 256; l < lg * 256 + 256; ++l) s += wp[l * P_];
      sm[lg * 96 + p] = s;
    }
    __syncthreads();
    if (tid < 96) s2[e * 96 + tid] = sm[tid] + sm[96 + tid];
  }
}

// logits: register-tiled LDS GEMM. Block = (b, 64-token tile, K-half).
__global__ __launch_bounds__(128) void k_logits(const float* __restrict__ x,
        const float* __restrict__ M, float* __restrict__ A0,
        float* __restrict__ A1) {
  __shared__ float xs[64 * 132];
  __shared__ float Ms[32 * 132];
  int dh = blockIdx.x & 1;
  int nt8 = (blockIdx.x >> 1) & 7;
  int b = blockIdx.x >> 4;
  int tid = threadIdx.x;
  const float* xb = x + (b * N_ + nt8 * 64) * D_ + dh * 256;
  const float* Mb = M + dh * 256;
  float acc[4][4] = {{0.f}};
  for (int kc = 0; kc < 2; ++kc) {
    for (int idx = tid; idx < 2048; idx += 128) {
      int r = idx >> 5, c4 = (idx & 31) * 4;
      *(float4*)(xs + r * 132 + c4) = *(const float4*)(xb + r * D_ + kc * 128 + c4);
    }
    for (int idx = tid; idx < 1024; idx += 128) {
      int r = idx >> 5, c4 = (idx & 31) * 4;
      *(float4*)(Ms + r * 132 + c4) = *(const float4*)(Mb + r * D_ + kc * 128 + c4);
    }
    __syncthreads();
    int nt = tid & 15, ht = tid >> 4;
#pragma unroll 4
    for (int d4 = 0; d4 < 128; d4 += 4) {
      float4 xv[4], mv[4];
#pragma unroll
      for (int i = 0; i < 4; ++i)
        xv[i] = *(const float4*)(xs + (nt + 16 * i) * 132 + d4);
#pragma unroll
      for (int j = 0; j < 4; ++j)
        mv[j] = *(const float4*)(Ms + (ht + 8 * j) * 132 + d4);
#pragma unroll
      for (int i = 0; i < 4; ++i)
#pragma unroll
        for (int j = 0; j < 4; ++j) {
          float s = acc[i][j];
          s = fmaf(xv[i].x, mv[j].x, s);
          s = fmaf(xv[i].y, mv[j].y, s);
          s = fmaf(xv[i].z, mv[j].z, s);
          s = fmaf(xv[i].w, mv[j].w, s);
          acc[i][j] = s;
        }
    }
    __syncthreads();
  }
  int nt = tid & 15, ht = tid >> 4;
  float* Ad = dh ? A1 : A0;
#pragma unroll
  for (int j = 0; j < 4; ++j) {
    int he = ht + 8 * j;
#pragma unroll
    for (int i = 0; i < 4; ++i)
      Ad[(b * HE + he) * N_ + nt8 * 64 + nt + 16 * i] = acc[i][j];
  }
}

// k_u: fused softmax + FULL-n attention-sum + V-projection.
// Block = (b, he-group-of-4). he = g*4+j -> h = g>>1, e = (g&1)*4+j.
// No 'up' intermediate: u rows live in LDS; only ap (512 KB) hits global.
// Block id = g*32 + b so all 8 g-blocks of one b share an XCD (x[b] L2-hot).
__global__ __launch_bounds__(512) void k_u(const float* __restrict__ x,
        const float* __restrict__ A0, const float* __restrict__ A1,
        const float* __restrict__ c, const float* __restrict__ Wv,
        const float* __restrict__ bv, float* __restrict__ ap) {
  __shared__ __align__(16) char smem[49248];
  float* Ast  = (float*)smem;              // [512][4] P transposed
  float* part = (float*)(smem + 8192);     // [4][4][512] then [16][4][128]
  float* ust  = (float*)(smem + 40960);    // [512][4] u transposed
  float* mH   = (float*)(smem + 49152);    // 8
  float* sH   = (float*)(smem + 49184);    // 8
  float* mS   = (float*)(smem + 49216);    // 4
  float* iS   = (float*)(smem + 49232);    // 4
  int id = blockIdx.x;
  int b = id & 31, g = id >> 5;
  int h = g >> 1, eb = (g & 1) * 4;
  int tid = threadIdx.x;
  const float scale = 0.08838834764831845f;
  int wv = tid >> 6, lane = tid & 63;
  int he_l = wv >> 1, half = wv & 1;
  // ---- phase A: softmax stats (2 waves per he) ----
  {
    int heg = g * 4 + he_l;
    const float* r0 = A0 + (b * HE + heg) * N_;
    const float* r1 = A1 + (b * HE + heg) * N_;
    float cc = c[heg];
    float v[4];
    float m = -1e30f;
#pragma unroll
    for (int k = 0; k < 4; ++k) {
      int n = half * 256 + lane + k * 64;
      float vv = scale * (r0[n] + r1[n] + cc);
      v[k] = vv;
      m = fmaxf(m, vv);
    }
    m = fmaxf(m, __shfl_xor(m, 1)); m = fmaxf(m, __shfl_xor(m, 2));
    m = fmaxf(m, __shfl_xor(m, 4)); m = fmaxf(m, __shfl_xor(m, 8));
    m = fmaxf(m, __shfl_xor(m, 16)); m = fmaxf(m, __shfl_xor(m, 32));
    if (lane == 0) mH[wv] = m;
    __syncthreads();
    m = fmaxf(mH[he_l * 2], mH[he_l * 2 + 1]);
    if (lane == 0 && half == 0) mS[he_l] = m;
    float s = 0.f;
#pragma unroll
    for (int k = 0; k < 4; ++k) s += expf(v[k] - m);
    s += __shfl_xor(s, 1); s += __shfl_xor(s, 2); s += __shfl_xor(s, 4);
    s += __shfl_xor(s, 8); s += __shfl_xor(s, 16); s += __shfl_xor(s, 32);
    if (lane == 0) sH[wv] = s;
    __syncthreads();
    if (lane == 0 && half == 0) iS[he_l] = 1.0f / (sH[he_l * 2] + sH[he_l * 2 + 1]);
  }
  __syncthreads();
  // ---- phase B: Ast[n][j] = normalized probs ----
  for (int idx = tid; idx < 2048; idx += 512) {
    int hl = idx >> 9, n = idx & 511;
    int heg = g * 4 + hl;
    float vv = scale * (A0[(b * HE + heg) * N_ + n] + A1[(b * HE + heg) * N_ + n]
                        + c[heg]);
    Ast[n * 4 + hl] = expf(vv - mS[hl]) * iS[hl];
  }
  __syncthreads();
  // ---- phase C: u[j][d] = sum_n P[j][n] * x[b,n,d] (4-way n-split) ----
  {
    int ns = tid >> 7, dg = tid & 127;
    float4 acc[4];
#pragma unroll
    for (int j = 0; j < 4; ++j) acc[j] = (float4){0.f, 0.f, 0.f, 0.f};
    const float* xb = x + (b * N_ + ns * 128) * D_ + dg * 4;
    const float* ab = Ast + ns * 128 * 4;
#pragma unroll 4
    for (int n = 0; n < 128; ++n) {
      float4 xv = *(const float4*)(xb + n * D_);
      float4 av = *(const float4*)(ab + n * 4);
      acc[0].x = fmaf(av.x, xv.x, acc[0].x); acc[0].y = fmaf(av.x, xv.y, acc[0].y);
      acc[0].z = fmaf(av.x, xv.z, acc[0].z); acc[0].w = fmaf(av.x, xv.w, acc[0].w);
      acc[1].x = fmaf(av.y, xv.x, acc[1].x); acc[1].y = fmaf(av.y, xv.y, acc[1].y);
      acc[1].z = fmaf(av.y, xv.z, acc[1].z); acc[1].w = fmaf(av.y, xv.w, acc[1].w);
      acc[2].x = fmaf(av.z, xv.x, acc[2].x); acc[2].y = fmaf(av.z, xv.y, acc[2].y);
      acc[2].z = fmaf(av.z, xv.z, acc[2].z); acc[2].w = fmaf(av.z, xv.w, acc[2].w);
      acc[3].x = fmaf(av.w, xv.x, acc[3].x); acc[3].y = fmaf(av.w, xv.y, acc[3].y);
      acc[3].z = fmaf(av.w, xv.z, acc[3].z); acc[3].w = fmaf(av.w, xv.w, acc[3].w);
    }
#pragma unroll
    for (int j = 0; j < 4; ++j)
      *(float4*)(part + ns * 2048 + j * 512 + dg * 4) = acc[j];
  }
  __syncthreads();
  // ---- reduce 4 n-splits -> ust[d][j] ----
  {
    int d = tid;
    float4 s = {0.f, 0.f, 0.f, 0.f};
#pragma unroll
    for (int ns2 = 0; ns2 < 4; ++ns2) {
      s.x += part[ns2 * 2048 + 0 * 512 + d];
      s.y += part[ns2 * 2048 + 1 * 512 + d];
      s.z += part[ns2 * 2048 + 2 * 512 + d];
      s.w += part[ns2 * 2048 + 3 * 512 + d];
    }
    *(float4*)(ust + d * 4) = s;
  }
  __syncthreads();
  // ---- phase D: V-projection ap[e][c] = sum_d u[e][d]*Wv[d, h*128+c] ----
  {
    int kq = tid >> 5, cg = tid & 31, c4 = cg * 4;
    float4 a2[4];
#pragma unroll
    for (int j = 0; j < 4; ++j) a2[j] = (float4){0.f, 0.f, 0.f, 0.f};
    const float* wvp = Wv + h * 128 + c4;
#pragma unroll 4
    for (int d = kq * 32; d < kq * 32 + 32; ++d) {
      float4 w4 = *(const float4*)(wvp + d * D_);
      float4 uu = *(const float4*)(ust + d * 4);
      a2[0].x = fmaf(uu.x, w4.x, a2[0].x); a2[0].y = fmaf(uu.x, w4.y, a2[0].y);
      a2[0].z = fmaf(uu.x, w4.z, a2[0].z); a2[0].w = fmaf(uu.x, w4.w, a2[0].w);
      a2[1].x = fmaf(uu.y, w4.x, a2[1].x); a2[1].y = fmaf(uu.y, w4.y, a2[1].y);
      a2[1].z = fmaf(uu.y, w4.z, a2[1].z); a2[1].w = fmaf(uu.y, w4.w, a2[1].w);
      a2[2].x = fmaf(uu.z, w4.x, a2[2].x); a2[2].y = fmaf(uu.z, w4.y, a2[2].y);
      a2[2].z = fmaf(uu.z, w4.z, a2[2].z); a2[2].w = fmaf(uu.z, w4.w, a2[2].w);
      a2[3].x = fmaf(uu.w, w4.x, a2[3].x); a2[3].y = fmaf(uu.w, w4.y, a2[3].y);
      a2[3].z = fmaf(uu.w, w4.z, a2[3].z); a2[3].w = fmaf(uu.w, w4.w, a2[3].w);
    }
#pragma unroll
    for (int j = 0; j < 4; ++j)
      *(float4*)(part + kq * 512 + j * 128 + c4) = a2[j];
  }
  __syncthreads();
  // ---- reduce 16 K-splits + bias -> ap ----
  {
    int j = tid >> 7, cc = tid & 127;
    float s = 0.f;
#pragma unroll
    for (int kq2 = 0; kq2 < 16; ++kq2) s += part[kq2 * 512 + j * 128 + cc];
    ap[(b * E_ + eb + j) * D_ + h * 128 + cc] = s + bv[h * 128 + cc];
  }
}

// k_op: O-projection att[b,e,:] = ap[b,e,:] @ Wo + bo.
// Block = (b, col-quarter, e-half): 256 blocks, 16-way K-split inside.
__global__ __launch_bounds__(512) void k_op(const float* __restrict__ ap,
        const float* __restrict__ Wo, const float* __restrict__ bo,
        float* __restrict__ att) {
  __shared__ __align__(16) char smem[40960];
  float* apt  = (float*)smem;              // [512][4] ap rows transposed
  float* part = (float*)(smem + 8192);     // [16][4][128]
  int id = blockIdx.x;
  int b = id & 31, q2 = id >> 5;
  int cq = q2 >> 1, eh = q2 & 1;
  int tid = threadIdx.x;
  // stage 4 ap rows transposed
  {
    int j = tid >> 7, tl = tid & 127;
    const float* arow = ap + (b * E_ + eh * 4 + j) * D_;
#pragma unroll
    for (int k = 0; k < 4; ++k) {
      int i = tl + k * 128;
      apt[i * 4 + j] = arow[i];
    }
  }
  __syncthreads();
  {
    int kq = tid >> 5, cg = tid & 31, c4 = cg * 4;
    float4 a2[4];
#pragma unroll
    for (int j = 0; j < 4; ++j) a2[j] = (float4){0.f, 0.f, 0.f, 0.f};
    const float* wop = Wo + cq * 128 + c4;
#pragma unroll 4
    for (int d = kq * 32; d < kq * 32 + 32; ++d) {
      float4 w4 = *(const float4*)(wop + d * D_);
      float4 uu = *(const float4*)(apt + d * 4);
      a2[0].x = fmaf(uu.x, w4.x, a2[0].x); a2[0].y = fmaf(uu.x, w4.y, a2[0].y);
      a2[0].z = fmaf(uu.x, w4.z, a2[0].z); a2[0].w = fmaf(uu.x, w4.w, a2[0].w);
      a2[1].x = fmaf(uu.y, w4.x, a2[1].x); a2[1].y = fmaf(uu.y, w4.y, a2[1].y);
      a2[1].z = fmaf(uu.y, w4.z, a2[1].z); a2[1].w = fmaf(uu.y, w4.w, a2[1].w);
      a2[2].x = fmaf(uu.z, w4.x, a2[2].x); a2[2].y = fmaf(uu.z, w4.y, a2[2].y);
      a2[2].z = fmaf(uu.z, w4.z, a2[2].z); a2[2].w = fmaf(uu.z, w4.w, a2[2].w);
      a2[3].x = fmaf(uu.w, w4.x, a2[3].x); a2[3].y = fmaf(uu.w, w4.y, a2[3].y);
      a2[3].z = fmaf(uu.w, w4.z, a2[3].z); a2[3].w = fmaf(uu.w, w4.w, a2[3].w);
    }
#pragma unroll
    for (int j = 0; j < 4; ++j)
      *(float4*)(part + kq * 512 + j * 128 + c4) = a2[j];
  }
  __syncthreads();
  {
    int j = tid >> 7, cc = tid & 127;
    float s = 0.f;
#pragma unroll
    for (int kq2 = 0; kq2 < 16; ++kq2) s += part[kq2 * 512 + j * 128 + cc];
    att[(b * E_ + eh * 4 + j) * D_ + cq * 128 + cc] = s + bo[cq * 128 + cc];
  }
}

// routing (one wave per token) + fused zc
__global__ __launch_bounds__(256) void k_route2(const float* __restrict__ x,
        const float* __restrict__ att, const __hip_bfloat16* __restrict__ weff,
        const float* __restrict__ s2, const float* __restrict__ bc,
        const float* __restrict__ bp, int* __restrict__ cnt,
        int* __restrict__ tok, float* __restrict__ zc) {
  __shared__ float att_s[8 * D_];
  __shared__ float rn[8];
  __shared__ float red[4][520];
  __shared__ int blist[8][32];
  __shared__ int bcnt[8];
  int b = blockIdx.x >> 4, tile = blockIdx.x & 15;
  for (int idx = threadIdx.x; idx < 1024; idx += 256)
    *(float4*)(att_s + idx * 4) = *(const float4*)(att + b * E_ * D_ + idx * 4);
  if (threadIdx.x < 8) bcnt[threadIdx.x] = 0;
  __syncthreads();
  {
    int e = threadIdx.x >> 5, l = threadIdx.x & 31;
    float s = 0.f;
    for (int d0 = l; d0 < D_; d0 += 32) {
      float v = att_s[e * D_ + d0];
      s = fmaf(v, v, s);
    }
#pragma unroll
    for (int off = 16; off; off >>= 1) s += __shfl_xor(s, off);
    if (l == 0) rn[e] = 1.0f / sqrtf(s);
  }
  __syncthreads();
  int w = threadIdx.x >> 6, lane = threadIdx.x & 63;
  int e2 = lane & 7, ch = lane >> 3;
  float* rw = red[w];
  for (int i = 0; i < 8; ++i) {
    int t = b * N_ + tile * 32 + w * 8 + i;
    const float* xp = x + t * D_ + lane * 8;
    float4 xa = *(const float4*)xp;
    float4 xb4 = *(const float4*)(xp + 4);
    float p[8];
#pragma unroll
    for (int e = 0; e < 8; ++e) {
      const float* apt = att_s + e * D_ + lane * 8;
      float4 a0 = *(const float4*)apt;
      float4 a1 = *(const float4*)(apt + 4);
      float s = a0.x * xa.x;
      s = fmaf(a0.y, xa.y, s); s = fmaf(a0.z, xa.z, s); s = fmaf(a0.w, xa.w, s);
      s = fmaf(a1.x, xb4.x, s); s = fmaf(a1.y, xb4.y, s);
      s = fmaf(a1.z, xb4.z, s); s = fmaf(a1.w, xb4.w, s);
      p[e] = s;
    }
#pragma unroll
    for (int e = 0; e < 8; ++e) rw[e * 65 + lane] = p[e];
    float s = 0.f;
#pragma unroll
    for (int k = 0; k < 8; ++k) s += rw[e2 * 65 + ch * 8 + k];
    s += __shfl_xor(s, 8); s += __shfl_xor(s, 16); s += __shfl_xor(s, 32);
    float sc = s * rn[e2];
    int be = e2;
#pragma unroll
    for (int off = 1; off < 8; off <<= 1) {
      float o = __shfl_xor(sc, off);
      int oe = __shfl_xor(be, off);
      if (o > sc || (o == sc && oe < be)) { sc = o; be = oe; }
    }
    if (lane == 0) {
      int slot = atomicAdd(&bcnt[be], 1);
      blist[be][slot] = t;
    }
  }
  __syncthreads();
  {
    int e = threadIdx.x >> 5, r = threadIdx.x & 31;
    int ce = bcnt[e];
    int gs = 0;
    if (r == 0 && ce > 0) gs = atomicAdd(&cnt[e * 32], ce);
    gs = __shfl(gs, (threadIdx.x & 63) & 32);
    for (int k2 = r; k2 < ce; k2 += 32) tok[e * BN + gs + k2] = blist[e][k2];
  }
  int grp = threadIdx.x >> 4, l16 = threadIdx.x & 15;
  for (int r = 0; r < 3; ++r) {
    int P = tile * 48 + r * 16 + grp;
    int ez = P / 96, p = P - ez * 96;
    const short* wrow = (const short*)weff + (((ez * 2 + 1) * P_ + p) << 9);
    const float* arow = att_s + ez * D_;
    float acc = 0.f;
#pragma unroll
    for (int seg = 0; seg < 4; ++seg) {
      int d = seg * 128 + l16 * 8;
      short8 w8 = *(const short8*)(wrow + d);
      const float* a8 = arow + d;
      acc = fmaf(a8[0], b2f(w8[0]), acc); acc = fmaf(a8[1], b2f(w8[1]), acc);
      acc = fmaf(a8[2], b2f(w8[2]), acc); acc = fmaf(a8[3], b2f(w8[3]), acc);
      acc = fmaf(a8[4], b2f(w8[4]), acc); acc = fmaf(a8[5], b2f(w8[5]), acc);
      acc = fmaf(a8[6], b2f(w8[6]), acc); acc = fmaf(a8[7], b2f(w8[7]), acc);
    }
    acc += __shfl_xor(acc, 1); acc += __shfl_xor(acc, 2);
    acc += __shfl_xor(acc, 4); acc += __shfl_xor(acc, 8);
    if (l16 == 0)
      zc[(b * E_ + ez) * P_ + p] = acc + bc[ez] * s2[ez * 96 + p] + bp[ez * 96 + p];
  }
}

// grouped final GEMM: exactly-sized segmented grid, 256 threads (4 waves),
// 32 tokens x 96 cols per block.
__global__ __launch_bounds__(256) void k_final(const float* __restrict__ x,
        const __hip_bfloat16* __restrict__ weff, const float* __restrict__ zc,
        const int* __restrict__ cnt, const int* __restrict__ tok,
        float* __restrict__ out) {
  __shared__ __align__(16) unsigned short xsb[32 * 520];
  __shared__ int toks[32];
  int g = blockIdx.x;
  int cl_e[E_], bs[E_ + 1];
  bs[0] = 0;
#pragma unroll
  for (int e = 0; e < E_; ++e) {
    cl_e[e] = cnt[e * 32];
    bs[e + 1] = bs[e] + ((cl_e[e] + 31) >> 5);
  }
  if (g >= bs[E_]) return;
  int e = 0;
#pragma unroll
  for (int k = 1; k < E_; ++k) if (g >= bs[k]) e = k;
  int base = (g - bs[e]) * 32;
  int cnt_e = cl_e[e];
  int cl = cnt_e - base; if (cl > 32) cl = 32;
  int tid = threadIdx.x;
  if (tid < 32) toks[tid] = (tid < cl) ? tok[e * BN + base + tid] : tok[e * BN + base];
  __syncthreads();
  for (int idx = tid; idx < 32 * 128; idx += 256) {
    int r = idx >> 7, c4 = (idx & 127) * 4;
    float4 v = *(const float4*)(x + toks[r] * D_ + c4);
    ushort4 u4;
    u4.x = f2b(v.x); u4.y = f2b(v.y); u4.z = f2b(v.z); u4.w = f2b(v.w);
    *(ushort4*)(xsb + r * 520 + c4) = u4;
  }
  __syncthreads();
  int wave = tid >> 6, lane = tid & 63;
  int mw = wave & 1, nw = wave >> 1;
  int m16 = lane & 15, quad = lane >> 4;
  const short* w0 = (const short*)(weff + (e * 2 + 0) * P_ * D_);
  f32x4 acc[3];
#pragma unroll
  for (int nt = 0; nt < 3; ++nt) acc[nt] = (f32x4){0.f, 0.f, 0.f, 0.f};
  const short* arow = (const short*)xsb + (mw * 16 + m16) * 520 + quad * 8;
  const short* brow = w0 + (nw * 48 + m16) * D_ + quad * 8;
  for (int kt = 0; kt < 16; ++kt) {
    int koff = kt * 32;
    short8 a = *(const short8*)(arow + koff);
#pragma unroll
    for (int nt = 0; nt < 3; ++nt) {
      short8 bf = *(const short8*)(brow + nt * 16 * D_ + koff);
      acc[nt] = __builtin_amdgcn_mfma_f32_16x16x32_bf16(a, bf, acc[nt], 0, 0, 0);
    }
  }
#pragma unroll
  for (int nt = 0; nt < 3; ++nt)
#pragma unroll
    for (int rr = 0; rr < 4; ++rr) {
      int row = mw * 16 + quad * 4 + rr;
      if (row < cl) {
        int tg = toks[row];
        int bb = tg >> 9;
        int p = nw * 48 + nt * 16 + m16;
        out[tg * P_ + p] = acc[nt][rr] + zc[(bb * E_ + e) * P_ + p];
      }
    }
}

extern "C" void kernel_launch(void* const* d_in, const int* in_sizes, int n_in,
                              void* d_out, int out_size, void* d_ws, size_t ws_size,
                              hipStream_t stream) {
  const float* x      = (const float*)d_in[0];
  const float* router = (const float*)d_in[1];
  const float* Wq     = (const float*)d_in[2];
  const float* bq     = (const float*)d_in[3];
  const float* Wk     = (const float*)d_in[4];
  const float* bk     = (const float*)d_in[5];
  const float* Wv     = (const float*)d_in[6];
  const float* bv     = (const float*)d_in[7];
  const float* Wo     = (const float*)d_in[8];
  const float* bo     = (const float*)d_in[9];
  const float* Wc     = (const float*)d_in[10];
  const float* bc     = (const float*)d_in[11];
  const float* Wp     = (const float*)d_in[12];
  const float* bp     = (const float*)d_in[13];
  float* out = (float*)d_out;
  float* w = (float*)d_ws;

  int*   cnt  = (int*)(w + OCNT);
  float* s2   = w + OS2;
  float* M    = w + OM;
  float* c    = w + OC;
  float* A0   = w + OA;
  float* A1   = w + OA1;
  float* att  = w + OATT;
  int*   tok  = (int*)(w + OTOK);
  __hip_bfloat16* weff = (__hip_bfloat16*)(w + OWEFF);
  float* zc   = w + OZC;
  float* ap   = w + OAP;

  k_head<<<200, 256, 0, stream>>>(router, Wq, bq, Wk, bk, Wp, Wc, M, c, cnt, s2, weff);
  k_logits<<<512, 128, 0, stream>>>(x, M, A0, A1);
  k_u<<<256, 512, 0, stream>>>(x, A0, A1, c, Wv, bv, ap);
  k_op<<<256, 512, 0, stream>>>(ap, Wo, bo, att);
  k_route2<<<512, 256, 0, stream>>>(x, att, weff, s2, bc, bp, cnt, tok, zc);
  k_final<<<520, 256, 0, stream>>>(x, weff, zc, cnt, tok, out);
}

// Round 5
// 199.053 us; speedup vs baseline: 1.7263x; 1.0485x over previous
//
#include <hip/hip_runtime.h>
#include <hip/hip_bf16.h>

#define B_ 32
#define N_ 512
#define D_ 512
#define E_ 8
#define P_ 96
#define KC 25
#define H_ 4
#define DK 128
#define HE 32
#define BN 16384

typedef short short8 __attribute__((ext_vector_type(8)));
typedef float f32x4 __attribute__((ext_vector_type(4)));

// ws offsets (floats). cnt zeroed + s2 computed race-free inside k_head.
#define OCNT  4096      /* 256 ints (8 counters strided by 32) */
#define OS2   4352      /* 768 */
#define OM    5120      /* 16384 */
#define OC    21504     /* 32 */
#define OA    21536     /* 524288: raw logits half-0 */
#define OATT  676896    /* 131072 */
#define OTOK  807968    /* 131072 ints */
#define OWEFF 939040    /* 786432 bf16 = 393216 float slots */
#define OZC   1332256   /* 24576 */
#define OA1   5551136   /* 524288: raw logits half-1 */
#define OAP   16777216  /* 131072: ap[b,e,512] V-projection output */

__device__ __forceinline__ float b2f(short s) {
  unsigned u = ((unsigned)(unsigned short)s) << 16;
  return __builtin_bit_cast(float, u);
}
__device__ __forceinline__ unsigned short f2b(float f) {
  return __builtin_bit_cast(unsigned short, __float2bfloat16(f));
}

// k_head (shrunk): M/c (64 blocks) + s2/cnt (8 blocks). weff moved to k_u grid.
__global__ __launch_bounds__(256) void k_head(const float* __restrict__ router,
        const float* __restrict__ Wq, const float* __restrict__ bq,
        const float* __restrict__ Wk, const float* __restrict__ bk,
        const float* __restrict__ Wp,
        float* __restrict__ M, float* __restrict__ c,
        int* __restrict__ cnt, float* __restrict__ s2) {
  __shared__ float sm[896];
  int bid = blockIdx.x;
  int tid = threadIdx.x;
  if (bid < 64) {
    float* rs = sm;
    float* ps = sm + 512;
    float* qs = sm + 768;
    int he = bid >> 1, ch = bid & 1;
    int h = he >> 3, e = he & 7;
    for (int i = tid; i < 512; i += 256) rs[i] = router[e * D_ + i];
    __syncthreads();
    {
      int j = tid & 127, dh = tid >> 7;
      const float* wq = Wq + h * 128 + j;
      float acc = 0.f;
      for (int d = dh * 256; d < dh * 256 + 256; d += 4) {
        acc = fmaf(rs[d], wq[d * D_], acc);
        acc = fmaf(rs[d + 1], wq[(d + 1) * D_], acc);
        acc = fmaf(rs[d + 2], wq[(d + 2) * D_], acc);
        acc = fmaf(rs[d + 3], wq[(d + 3) * D_], acc);
      }
      ps[dh * 128 + j] = acc;
    }
    __syncthreads();
    if (tid < 128) qs[tid] = ps[tid] + ps[128 + tid] + bq[h * 128 + tid];
    __syncthreads();
    {
      int d0 = ch * 256 + tid;
      const float* wrow = Wk + d0 * D_ + h * 128;
      float acc = 0.f;
      for (int jj = 0; jj < 128; jj += 4) {
        float4 wv = *(const float4*)(wrow + jj);
        acc = fmaf(wv.x, qs[jj], acc);
        acc = fmaf(wv.y, qs[jj + 1], acc);
        acc = fmaf(wv.z, qs[jj + 2], acc);
        acc = fmaf(wv.w, qs[jj + 3], acc);
      }
      M[he * D_ + d0] = acc;
    }
    if (ch == 0 && tid < 64) {
      float s = qs[tid] * bk[h * 128 + tid] + qs[tid + 64] * bk[h * 128 + tid + 64];
#pragma unroll
      for (int off = 32; off; off >>= 1) s += __shfl_xor(s, off);
      if (tid == 0) c[he] = s;
    }
  } else {
    int e = bid - 64;
    if (bid == 64) cnt[tid] = 0;
    if (tid < 192) {
      int p = tid % 96, lg = tid / 96;
      float s = 0.f;
      const float* wp = Wp + e * D_ * P_ + p;
      for (int l = lg * 256; l < lg * 256 + 256; ++l) s += wp[l * P_];
      sm[lg * 96 + p] = s;
    }
    __syncthreads();
    if (tid < 96) s2[e * 96 + tid] = sm[tid] + sm[96 + tid];
  }
}

// logits: register-tiled LDS GEMM. Block = (b, 64-token tile, K-half).
__global__ __launch_bounds__(128) void k_logits(const float* __restrict__ x,
        const float* __restrict__ M, float* __restrict__ A0,
        float* __restrict__ A1) {
  __shared__ float xs[64 * 132];
  __shared__ float Ms[32 * 132];
  int dh = blockIdx.x & 1;
  int nt8 = (blockIdx.x >> 1) & 7;
  int b = blockIdx.x >> 4;
  int tid = threadIdx.x;
  const float* xb = x + (b * N_ + nt8 * 64) * D_ + dh * 256;
  const float* Mb = M + dh * 256;
  float acc[4][4] = {{0.f}};
  for (int kc = 0; kc < 2; ++kc) {
    for (int idx = tid; idx < 2048; idx += 128) {
      int r = idx >> 5, c4 = (idx & 31) * 4;
      *(float4*)(xs + r * 132 + c4) = *(const float4*)(xb + r * D_ + kc * 128 + c4);
    }
    for (int idx = tid; idx < 1024; idx += 128) {
      int r = idx >> 5, c4 = (idx & 31) * 4;
      *(float4*)(Ms + r * 132 + c4) = *(const float4*)(Mb + r * D_ + kc * 128 + c4);
    }
    __syncthreads();
    int nt = tid & 15, ht = tid >> 4;
#pragma unroll 4
    for (int d4 = 0; d4 < 128; d4 += 4) {
      float4 xv[4], mv[4];
#pragma unroll
      for (int i = 0; i < 4; ++i)
        xv[i] = *(const float4*)(xs + (nt + 16 * i) * 132 + d4);
#pragma unroll
      for (int j = 0; j < 4; ++j)
        mv[j] = *(const float4*)(Ms + (ht + 8 * j) * 132 + d4);
#pragma unroll
      for (int i = 0; i < 4; ++i)
#pragma unroll
        for (int j = 0; j < 4; ++j) {
          float s = acc[i][j];
          s = fmaf(xv[i].x, mv[j].x, s);
          s = fmaf(xv[i].y, mv[j].y, s);
          s = fmaf(xv[i].z, mv[j].z, s);
          s = fmaf(xv[i].w, mv[j].w, s);
          acc[i][j] = s;
        }
    }
    __syncthreads();
  }
  int nt = tid & 15, ht = tid >> 4;
  float* Ad = dh ? A1 : A0;
#pragma unroll
  for (int j = 0; j < 4; ++j) {
    int he = ht + 8 * j;
#pragma unroll
    for (int i = 0; i < 4; ++i)
      Ad[(b * HE + he) * N_ + nt8 * 64 + nt + 16 * i] = acc[i][j];
  }
}

// k_u: fused softmax + FULL-n attention-sum + V-projection (bid < 256),
// plus weff preprocessing blocks (bid >= 256, moved off k_head's critical path).
// u-block = (b, he-group-of-4). he = g*4+j -> h = g>>1, e = (g&1)*4+j.
// Block id = g*32 + b so all 8 g-blocks of one b share an XCD (x[b] L2-hot).
// Register-P: probs computed once in phase A registers, written to LDS directly.
__global__ __launch_bounds__(512) void k_u(const float* __restrict__ x,
        const float* __restrict__ A0, const float* __restrict__ A1,
        const float* __restrict__ c, const float* __restrict__ Wv,
        const float* __restrict__ bv, const float* __restrict__ Wp,
        const float* __restrict__ Wc, __hip_bfloat16* __restrict__ weff,
        float* __restrict__ ap) {
  __shared__ __align__(16) char smem[49248];
  int tid = threadIdx.x;
  if (blockIdx.x >= 256) {
    // ---- weff: effective conv weights (from old k_head mid-branch) ----
    float* T = (float*)smem;
    float* wcs = (float*)smem + 5760;
    int eb = blockIdx.x - 256;
    int e = eb >> 4, mc = eb & 15;
    int lo = mc * 32 - 12;
    for (int idx = tid; idx < 56 * 24; idx += 512) {
      int lp = idx / 24, p4 = (idx - lp * 24) * 4;
      int l = lo + lp;
      float4 v = {0.f, 0.f, 0.f, 0.f};
      if (l >= 0 && l < D_) v = *(const float4*)(Wp + (e * D_ + l) * P_ + p4);
      T[p4 * 60 + lp] = v.x; T[(p4 + 1) * 60 + lp] = v.y;
      T[(p4 + 2) * 60 + lp] = v.z; T[(p4 + 3) * 60 + lp] = v.w;
    }
    if (tid < 50) wcs[tid] = Wc[e * 2 * KC + tid];
    __syncthreads();
    if (tid < 256) {
      int m = tid & 31, pg = tid >> 5;
#pragma unroll
      for (int j = 0; j < 2; ++j)
        for (int k2 = 0; k2 < 12; ++k2) {
          int p = pg * 12 + k2;
          float acc = 0.f;
#pragma unroll
          for (int k = 0; k < KC; ++k)
            acc = fmaf(wcs[j * 25 + k], T[p * 60 + m - k + 24], acc);
          weff[(((e * 2 + j) * P_ + p) << 9) + mc * 32 + m] = __float2bfloat16(acc);
        }
    }
    return;
  }
  float* Ast  = (float*)smem;              // [512][4] P transposed
  float* part = (float*)(smem + 8192);     // [4][4][512] then [16][4][128]
  float* ust  = (float*)(smem + 40960);    // [512][4] u transposed
  float* mH   = (float*)(smem + 49152);    // 8
  float* sH   = (float*)(smem + 49184);    // 8
  int id = blockIdx.x;
  int b = id & 31, g = id >> 5;
  int h = g >> 1, eb2 = (g & 1) * 4;
  const float scale = 0.08838834764831845f;
  int wv = tid >> 6, lane = tid & 63;
  int he_l = wv >> 1, half = wv & 1;
  // ---- phase A: softmax stats + probs fully in registers (2 waves per he) ----
  float p[4];
  {
    int heg = g * 4 + he_l;
    const float* r0 = A0 + (b * HE + heg) * N_;
    const float* r1 = A1 + (b * HE + heg) * N_;
    float cc = c[heg];
    float v[4];
    float m = -1e30f;
#pragma unroll
    for (int k = 0; k < 4; ++k) {
      int n = half * 256 + lane + k * 64;
      float vv = scale * (r0[n] + r1[n] + cc);
      v[k] = vv;
      m = fmaxf(m, vv);
    }
    m = fmaxf(m, __shfl_xor(m, 1)); m = fmaxf(m, __shfl_xor(m, 2));
    m = fmaxf(m, __shfl_xor(m, 4)); m = fmaxf(m, __shfl_xor(m, 8));
    m = fmaxf(m, __shfl_xor(m, 16)); m = fmaxf(m, __shfl_xor(m, 32));
    if (lane == 0) mH[wv] = m;
    __syncthreads();
    m = fmaxf(mH[he_l * 2], mH[he_l * 2 + 1]);
    float s = 0.f;
#pragma unroll
    for (int k = 0; k < 4; ++k) { p[k] = expf(v[k] - m); s += p[k]; }
    s += __shfl_xor(s, 1); s += __shfl_xor(s, 2); s += __shfl_xor(s, 4);
    s += __shfl_xor(s, 8); s += __shfl_xor(s, 16); s += __shfl_xor(s, 32);
    if (lane == 0) sH[wv] = s;
  }
  __syncthreads();
  // ---- phase B: write normalized probs from registers ----
  {
    float is_ = 1.0f / (sH[he_l * 2] + sH[he_l * 2 + 1]);
#pragma unroll
    for (int k = 0; k < 4; ++k) {
      int n = half * 256 + lane + k * 64;
      Ast[n * 4 + he_l] = p[k] * is_;
    }
  }
  __syncthreads();
  // ---- phase C: u[j][d] = sum_n P[j][n] * x[b,n,d] (4-way n-split) ----
  {
    int ns = tid >> 7, dg = tid & 127;
    float4 acc[4];
#pragma unroll
    for (int j = 0; j < 4; ++j) acc[j] = (float4){0.f, 0.f, 0.f, 0.f};
    const float* xb = x + (b * N_ + ns * 128) * D_ + dg * 4;
    const float* ab = Ast + ns * 128 * 4;
#pragma unroll 4
    for (int n = 0; n < 128; ++n) {
      float4 xv = *(const float4*)(xb + n * D_);
      float4 av = *(const float4*)(ab + n * 4);
      acc[0].x = fmaf(av.x, xv.x, acc[0].x); acc[0].y = fmaf(av.x, xv.y, acc[0].y);
      acc[0].z = fmaf(av.x, xv.z, acc[0].z); acc[0].w = fmaf(av.x, xv.w, acc[0].w);
      acc[1].x = fmaf(av.y, xv.x, acc[1].x); acc[1].y = fmaf(av.y, xv.y, acc[1].y);
      acc[1].z = fmaf(av.y, xv.z, acc[1].z); acc[1].w = fmaf(av.y, xv.w, acc[1].w);
      acc[2].x = fmaf(av.z, xv.x, acc[2].x); acc[2].y = fmaf(av.z, xv.y, acc[2].y);
      acc[2].z = fmaf(av.z, xv.z, acc[2].z); acc[2].w = fmaf(av.z, xv.w, acc[2].w);
      acc[3].x = fmaf(av.w, xv.x, acc[3].x); acc[3].y = fmaf(av.w, xv.y, acc[3].y);
      acc[3].z = fmaf(av.w, xv.z, acc[3].z); acc[3].w = fmaf(av.w, xv.w, acc[3].w);
    }
#pragma unroll
    for (int j = 0; j < 4; ++j)
      *(float4*)(part + ns * 2048 + j * 512 + dg * 4) = acc[j];
  }
  __syncthreads();
  // ---- reduce 4 n-splits -> ust[d][j] ----
  {
    int d = tid;
    float4 s = {0.f, 0.f, 0.f, 0.f};
#pragma unroll
    for (int ns2 = 0; ns2 < 4; ++ns2) {
      s.x += part[ns2 * 2048 + 0 * 512 + d];
      s.y += part[ns2 * 2048 + 1 * 512 + d];
      s.z += part[ns2 * 2048 + 2 * 512 + d];
      s.w += part[ns2 * 2048 + 3 * 512 + d];
    }
    *(float4*)(ust + d * 4) = s;
  }
  __syncthreads();
  // ---- phase D: V-projection ap[e][c] = sum_d u[e][d]*Wv[d, h*128+c] ----
  {
    int kq = tid >> 5, cg = tid & 31, c4 = cg * 4;
    float4 a2[4];
#pragma unroll
    for (int j = 0; j < 4; ++j) a2[j] = (float4){0.f, 0.f, 0.f, 0.f};
    const float* wvp = Wv + h * 128 + c4;
#pragma unroll 4
    for (int d = kq * 32; d < kq * 32 + 32; ++d) {
      float4 w4 = *(const float4*)(wvp + d * D_);
      float4 uu = *(const float4*)(ust + d * 4);
      a2[0].x = fmaf(uu.x, w4.x, a2[0].x); a2[0].y = fmaf(uu.x, w4.y, a2[0].y);
      a2[0].z = fmaf(uu.x, w4.z, a2[0].z); a2[0].w = fmaf(uu.x, w4.w, a2[0].w);
      a2[1].x = fmaf(uu.y, w4.x, a2[1].x); a2[1].y = fmaf(uu.y, w4.y, a2[1].y);
      a2[1].z = fmaf(uu.y, w4.z, a2[1].z); a2[1].w = fmaf(uu.y, w4.w, a2[1].w);
      a2[2].x = fmaf(uu.z, w4.x, a2[2].x); a2[2].y = fmaf(uu.z, w4.y, a2[2].y);
      a2[2].z = fmaf(uu.z, w4.z, a2[2].z); a2[2].w = fmaf(uu.z, w4.w, a2[2].w);
      a2[3].x = fmaf(uu.w, w4.x, a2[3].x); a2[3].y = fmaf(uu.w, w4.y, a2[3].y);
      a2[3].z = fmaf(uu.w, w4.z, a2[3].z); a2[3].w = fmaf(uu.w, w4.w, a2[3].w);
    }
#pragma unroll
    for (int j = 0; j < 4; ++j)
      *(float4*)(part + kq * 512 + j * 128 + c4) = a2[j];
  }
  __syncthreads();
  // ---- reduce 16 K-splits + bias -> ap ----
  {
    int j = tid >> 7, cc = tid & 127;
    float s = 0.f;
#pragma unroll
    for (int kq2 = 0; kq2 < 16; ++kq2) s += part[kq2 * 512 + j * 128 + cc];
    ap[(b * E_ + eb2 + j) * D_ + h * 128 + cc] = s + bv[h * 128 + cc];
  }
}

// k_op: O-projection att[b,e,:] = ap[b,e,:] @ Wo + bo.
// Block = (b, col-quarter, e-half): 256 blocks, 16-way K-split inside.
__global__ __launch_bounds__(512) void k_op(const float* __restrict__ ap,
        const float* __restrict__ Wo, const float* __restrict__ bo,
        float* __restrict__ att) {
  __shared__ __align__(16) char smem[40960];
  float* apt  = (float*)smem;              // [512][4] ap rows transposed
  float* part = (float*)(smem + 8192);     // [16][4][128]
  int id = blockIdx.x;
  int b = id & 31, q2 = id >> 5;
  int cq = q2 >> 1, eh = q2 & 1;
  int tid = threadIdx.x;
  // stage 4 ap rows transposed
  {
    int j = tid >> 7, tl = tid & 127;
    const float* arow = ap + (b * E_ + eh * 4 + j) * D_;
#pragma unroll
    for (int k = 0; k < 4; ++k) {
      int i = tl + k * 128;
      apt[i * 4 + j] = arow[i];
    }
  }
  __syncthreads();
  {
    int kq = tid >> 5, cg = tid & 31, c4 = cg * 4;
    float4 a2[4];
#pragma unroll
    for (int j = 0; j < 4; ++j) a2[j] = (float4){0.f, 0.f, 0.f, 0.f};
    const float* wop = Wo + cq * 128 + c4;
#pragma unroll 4
    for (int d = kq * 32; d < kq * 32 + 32; ++d) {
      float4 w4 = *(const float4*)(wop + d * D_);
      float4 uu = *(const float4*)(apt + d * 4);
      a2[0].x = fmaf(uu.x, w4.x, a2[0].x); a2[0].y = fmaf(uu.x, w4.y, a2[0].y);
      a2[0].z = fmaf(uu.x, w4.z, a2[0].z); a2[0].w = fmaf(uu.x, w4.w, a2[0].w);
      a2[1].x = fmaf(uu.y, w4.x, a2[1].x); a2[1].y = fmaf(uu.y, w4.y, a2[1].y);
      a2[1].z = fmaf(uu.y, w4.z, a2[1].z); a2[1].w = fmaf(uu.y, w4.w, a2[1].w);
      a2[2].x = fmaf(uu.z, w4.x, a2[2].x); a2[2].y = fmaf(uu.z, w4.y, a2[2].y);
      a2[2].z = fmaf(uu.z, w4.z, a2[2].z); a2[2].w = fmaf(uu.z, w4.w, a2[2].w);
      a2[3].x = fmaf(uu.w, w4.x, a2[3].x); a2[3].y = fmaf(uu.w, w4.y, a2[3].y);
      a2[3].z = fmaf(uu.w, w4.z, a2[3].z); a2[3].w = fmaf(uu.w, w4.w, a2[3].w);
    }
#pragma unroll
    for (int j = 0; j < 4; ++j)
      *(float4*)(part + kq * 512 + j * 128 + c4) = a2[j];
  }
  __syncthreads();
  {
    int j = tid >> 7, cc = tid & 127;
    float s = 0.f;
#pragma unroll
    for (int kq2 = 0; kq2 < 16; ++kq2) s += part[kq2 * 512 + j * 128 + cc];
    att[(b * E_ + eh * 4 + j) * D_ + cq * 128 + cc] = s + bo[cq * 128 + cc];
  }
}

// routing + fused zc: 256 blocks x 512 thr, 64-token tiles (was 512x256/32).
// Halves att-staging + rn redundancy; zc expert = tile.
__global__ __launch_bounds__(512) void k_route2(const float* __restrict__ x,
        const float* __restrict__ att, const __hip_bfloat16* __restrict__ weff,
        const float* __restrict__ s2, const float* __restrict__ bc,
        const float* __restrict__ bp, int* __restrict__ cnt,
        int* __restrict__ tok, float* __restrict__ zc) {
  __shared__ float att_s[8 * D_];
  __shared__ float rn[8];
  __shared__ float red[8][520];
  __shared__ int blist[8][64];
  __shared__ int bcnt[8];
  int b = blockIdx.x >> 3, tile = blockIdx.x & 7;
  int tid = threadIdx.x;
  for (int idx = tid; idx < 1024; idx += 512)
    *(float4*)(att_s + idx * 4) = *(const float4*)(att + b * E_ * D_ + idx * 4);
  if (tid < 8) bcnt[tid] = 0;
  __syncthreads();
  if (tid < 256) {
    int e = tid >> 5, l = tid & 31;
    float s = 0.f;
    for (int d0 = l; d0 < D_; d0 += 32) {
      float v = att_s[e * D_ + d0];
      s = fmaf(v, v, s);
    }
#pragma unroll
    for (int off = 16; off; off >>= 1) s += __shfl_xor(s, off);
    if (l == 0) rn[e] = 1.0f / sqrtf(s);
  }
  __syncthreads();
  int w = tid >> 6, lane = tid & 63;
  int e2 = lane & 7, ch = lane >> 3;
  float* rw = red[w];
  for (int i = 0; i < 8; ++i) {
    int t = b * N_ + tile * 64 + w * 8 + i;
    const float* xp = x + t * D_ + lane * 8;
    float4 xa = *(const float4*)xp;
    float4 xb4 = *(const float4*)(xp + 4);
    float p[8];
#pragma unroll
    for (int e = 0; e < 8; ++e) {
      const float* apt = att_s + e * D_ + lane * 8;
      float4 a0 = *(const float4*)apt;
      float4 a1 = *(const float4*)(apt + 4);
      float s = a0.x * xa.x;
      s = fmaf(a0.y, xa.y, s); s = fmaf(a0.z, xa.z, s); s = fmaf(a0.w, xa.w, s);
      s = fmaf(a1.x, xb4.x, s); s = fmaf(a1.y, xb4.y, s);
      s = fmaf(a1.z, xb4.z, s); s = fmaf(a1.w, xb4.w, s);
      p[e] = s;
    }
#pragma unroll
    for (int e = 0; e < 8; ++e) rw[e * 65 + lane] = p[e];
    float s = 0.f;
#pragma unroll
    for (int k = 0; k < 8; ++k) s += rw[e2 * 65 + ch * 8 + k];
    s += __shfl_xor(s, 8); s += __shfl_xor(s, 16); s += __shfl_xor(s, 32);
    float sc = s * rn[e2];
    int be = e2;
#pragma unroll
    for (int off = 1; off < 8; off <<= 1) {
      float o = __shfl_xor(sc, off);
      int oe = __shfl_xor(be, off);
      if (o > sc || (o == sc && oe < be)) { sc = o; be = oe; }
    }
    if (lane == 0) {
      int slot = atomicAdd(&bcnt[be], 1);
      blist[be][slot] = t;
    }
  }
  __syncthreads();
  if (tid < 256) {
    int e = tid >> 5, r = tid & 31;
    int ce = bcnt[e];
    int gs = 0;
    if (r == 0 && ce > 0) gs = atomicAdd(&cnt[e * 32], ce);
    gs = __shfl(gs, (tid & 63) & 32);
    for (int k2 = r; k2 < ce; k2 += 32) tok[e * BN + gs + k2] = blist[e][k2];
  }
  int grp = tid >> 4, l16 = tid & 15;
  const float* arow = att_s + tile * D_;
  for (int r = 0; r < 3; ++r) {
    int p = r * 32 + grp;
    const short* wrow = (const short*)weff + (((tile * 2 + 1) * P_ + p) << 9);
    float acc = 0.f;
#pragma unroll
    for (int seg = 0; seg < 4; ++seg) {
      int d = seg * 128 + l16 * 8;
      short8 w8 = *(const short8*)(wrow + d);
      const float* a8 = arow + d;
      acc = fmaf(a8[0], b2f(w8[0]), acc); acc = fmaf(a8[1], b2f(w8[1]), acc);
      acc = fmaf(a8[2], b2f(w8[2]), acc); acc = fmaf(a8[3], b2f(w8[3]), acc);
      acc = fmaf(a8[4], b2f(w8[4]), acc); acc = fmaf(a8[5], b2f(w8[5]), acc);
      acc = fmaf(a8[6], b2f(w8[6]), acc); acc = fmaf(a8[7], b2f(w8[7]), acc);
    }
    acc += __shfl_xor(acc, 1); acc += __shfl_xor(acc, 2);
    acc += __shfl_xor(acc, 4); acc += __shfl_xor(acc, 8);
    if (l16 == 0)
      zc[(b * E_ + tile) * P_ + p] = acc + bc[tile] * s2[tile * 96 + p]
                                     + bp[tile * 96 + p];
  }
}

// grouped final GEMM: exactly-sized segmented grid, 256 threads (4 waves),
// 32 tokens x 96 cols per block.
__global__ __launch_bounds__(256) void k_final(const float* __restrict__ x,
        const __hip_bfloat16* __restrict__ weff, const float* __restrict__ zc,
        const int* __restrict__ cnt, const int* __restrict__ tok,
        float* __restrict__ out) {
  __shared__ __align__(16) unsigned short xsb[32 * 520];
  __shared__ int toks[32];
  int g = blockIdx.x;
  int cl_e[E_], bs[E_ + 1];
  bs[0] = 0;
#pragma unroll
  for (int e = 0; e < E_; ++e) {
    cl_e[e] = cnt[e * 32];
    bs[e + 1] = bs[e] + ((cl_e[e] + 31) >> 5);
  }
  if (g >= bs[E_]) return;
  int e = 0;
#pragma unroll
  for (int k = 1; k < E_; ++k) if (g >= bs[k]) e = k;
  int base = (g - bs[e]) * 32;
  int cnt_e = cl_e[e];
  int cl = cnt_e - base; if (cl > 32) cl = 32;
  int tid = threadIdx.x;
  if (tid < 32) toks[tid] = (tid < cl) ? tok[e * BN + base + tid] : tok[e * BN + base];
  __syncthreads();
  for (int idx = tid; idx < 32 * 128; idx += 256) {
    int r = idx >> 7, c4 = (idx & 127) * 4;
    float4 v = *(const float4*)(x + toks[r] * D_ + c4);
    ushort4 u4;
    u4.x = f2b(v.x); u4.y = f2b(v.y); u4.z = f2b(v.z); u4.w = f2b(v.w);
    *(ushort4*)(xsb + r * 520 + c4) = u4;
  }
  __syncthreads();
  int wave = tid >> 6, lane = tid & 63;
  int mw = wave & 1, nw = wave >> 1;
  int m16 = lane & 15, quad = lane >> 4;
  const short* w0 = (const short*)(weff + (e * 2 + 0) * P_ * D_);
  f32x4 acc[3];
#pragma unroll
  for (int nt = 0; nt < 3; ++nt) acc[nt] = (f32x4){0.f, 0.f, 0.f, 0.f};
  const short* arow = (const short*)xsb + (mw * 16 + m16) * 520 + quad * 8;
  const short* brow = w0 + (nw * 48 + m16) * D_ + quad * 8;
  for (int kt = 0; kt < 16; ++kt) {
    int koff = kt * 32;
    short8 a = *(const short8*)(arow + koff);
#pragma unroll
    for (int nt = 0; nt < 3; ++nt) {
      short8 bf = *(const short8*)(brow + nt * 16 * D_ + koff);
      acc[nt] = __builtin_amdgcn_mfma_f32_16x16x32_bf16(a, bf, acc[nt], 0, 0, 0);
    }
  }
#pragma unroll
  for (int nt = 0; nt < 3; ++nt)
#pragma unroll
    for (int rr = 0; rr < 4; ++rr) {
      int row = mw * 16 + quad * 4 + rr;
      if (row < cl) {
        int tg = toks[row];
        int bb = tg >> 9;
        int p = nw * 48 + nt * 16 + m16;
        out[tg * P_ + p] = acc[nt][rr] + zc[(bb * E_ + e) * P_ + p];
      }
    }
}

extern "C" void kernel_launch(void* const* d_in, const int* in_sizes, int n_in,
                              void* d_out, int out_size, void* d_ws, size_t ws_size,
                              hipStream_t stream) {
  const float* x      = (const float*)d_in[0];
  const float* router = (const float*)d_in[1];
  const float* Wq     = (const float*)d_in[2];
  const float* bq     = (const float*)d_in[3];
  const float* Wk     = (const float*)d_in[4];
  const float* bk     = (const float*)d_in[5];
  const float* Wv     = (const float*)d_in[6];
  const float* bv     = (const float*)d_in[7];
  const float* Wo     = (const float*)d_in[8];
  const float* bo     = (const float*)d_in[9];
  const float* Wc     = (const float*)d_in[10];
  const float* bc     = (const float*)d_in[11];
  const float* Wp     = (const float*)d_in[12];
  const float* bp     = (const float*)d_in[13];
  float* out = (float*)d_out;
  float* w = (float*)d_ws;

  int*   cnt  = (int*)(w + OCNT);
  float* s2   = w + OS2;
  float* M    = w + OM;
  float* c    = w + OC;
  float* A0   = w + OA;
  float* A1   = w + OA1;
  float* att  = w + OATT;
  int*   tok  = (int*)(w + OTOK);
  __hip_bfloat16* weff = (__hip_bfloat16*)(w + OWEFF);
  float* zc   = w + OZC;
  float* ap   = w + OAP;

  k_head<<<72, 256, 0, stream>>>(router, Wq, bq, Wk, bk, Wp, M, c, cnt, s2);
  k_logits<<<512, 128, 0, stream>>>(x, M, A0, A1);
  k_u<<<384, 512, 0, stream>>>(x, A0, A1, c, Wv, bv, Wp, Wc, weff, ap);
  k_op<<<256, 512, 0, stream>>>(ap, Wo, bo, att);
  k_route2<<<256, 512, 0, stream>>>(x, att, weff, s2, bc, bp, cnt, tok, zc);
  k_final<<<520, 256, 0, stream>>>(x, weff, zc, cnt, tok, out);
}